// Round 14
// baseline (91.037 us; speedup 1.0000x reference)
//
#include <hip/hip_runtime.h>
#include <math.h>

#define BB 2
#define LL 1024
#define DD 512
#define HH 8
#define DHD 64
#define QQ 64
#define NCC 16

typedef __attribute__((ext_vector_type(8))) short s8b;   // 8 bf16 (4 VGPRs)
typedef __attribute__((ext_vector_type(4))) float f4;    // 4 fp32 acc

__device__ __forceinline__ void gld16(const void* g, void* l) {
    __builtin_amdgcn_global_load_lds(
        (const __attribute__((address_space(1))) unsigned int*)g,
        (__attribute__((address_space(3))) unsigned int*)l, 16, 0, 0);
}

__device__ __forceinline__ void bf16split(float f, unsigned short& h, unsigned short& l) {
    unsigned u  = __float_as_uint(f);
    unsigned hb = (u + 0x7FFFu + ((u >> 16) & 1u)) & 0xFFFF0000u;   // RTNE bf16
    float fh = __uint_as_float(hb);
    float fl = f - fh;
    unsigned ul = __float_as_uint(fl);
    unsigned lb = (ul + 0x7FFFu + ((ul >> 16) & 1u)) >> 16;
    h = (unsigned short)(hb >> 16);
    l = (unsigned short)lb;
}

__device__ __forceinline__ unsigned pk2(unsigned short a, unsigned short b) {
    return (unsigned)a | ((unsigned)b << 16);
}

// ---------------------------------------------------------------------------
// Kernel 0: split x / Wa / Wb / Wc into bf16 hi/lo arrays (unchanged).
// ---------------------------------------------------------------------------
__global__ __launch_bounds__(256) void convert_split(
    const float* __restrict__ x, const float* __restrict__ Wa,
    const float* __restrict__ Wb, const float* __restrict__ Wc,
    unsigned short* __restrict__ xh, unsigned short* __restrict__ xl,
    unsigned short* __restrict__ wh, unsigned short* __restrict__ wl)
{
    const int g = blockIdx.x * 256 + threadIdx.x;    // float4 index
    const float* src;
    unsigned short *dh, *dl;
    if (g < 262144) {
        const size_t off = (size_t)g * 4;
        src = x + off; dh = xh + off; dl = xl + off;
    } else {
        const size_t j = (size_t)(g - 262144) * 4;   // 0..786431
        const int wsel = (int)(j >> 18);             // 262144 elements each
        const size_t r = j & 262143;
        src = (wsel == 0 ? Wa : (wsel == 1 ? Wb : Wc)) + r;
        dh = wh + j; dl = wl + j;
    }
    const float4 v = *(const float4*)src;
    const float f[4] = {v.x, v.y, v.z, v.w};
    unsigned short h[4], l[4];
    #pragma unroll
    for (int i = 0; i < 4; ++i) bf16split(f[i], h[i], l[i]);
    *(uint2*)dh = make_uint2(pk2(h[0], h[1]), pk2(h[2], h[3]));
    *(uint2*)dl = make_uint2(pk2(l[0], l[1]), pk2(l[2], l[3]));
}

// ---------------------------------------------------------------------------
// Kernel 1: fused 3-weight MFMA GEMM, double-buffered, + csum epilogue
// (unchanged from R12: coalesced swizzled staging).
// ---------------------------------------------------------------------------
__global__ __launch_bounds__(512) void gemm3_fused(
    const unsigned short* __restrict__ xh, const unsigned short* __restrict__ xl,
    const unsigned short* __restrict__ wh, const unsigned short* __restrict__ wl,
    const float* __restrict__ ba, const float* __restrict__ bb, const float* __restrict__ bc,
    float* __restrict__ logA, float* __restrict__ Bf, float* __restrict__ Cf,
    float* __restrict__ csum)
{
    __shared__ unsigned char lds[65536];
    __shared__ float csv[64];

    const int bm = blockIdx.x >> 3;
    const int bn = blockIdx.x & 7;
    const int m0 = bm << 6, o0 = bn << 6;
    const int t = threadIdx.x, wv = t >> 6, ln = t & 63;
    const int l15 = ln & 15, l4 = ln >> 4;
    const int wr = (wv >> 2) << 5;      // 0 / 32
    const int wc = (wv & 3) << 4;       // 0 / 16 / 32 / 48

    const unsigned short* hp = (wv < 2) ? xh : wh + (size_t)((wv - 2) >> 1) * 262144;
    const unsigned short* lp = (wv < 2) ? xl : wl + (size_t)((wv - 2) >> 1) * 262144;
    const unsigned short* sp2 = ((wv & 1) ? lp : hp) + (size_t)((wv < 2) ? m0 : o0) * DD;
    const int abase = wv * 4096;

    const int rl = ln >> 2;          // row within 16-row group
    const int sl = ln & 3;           // stored slot
    size_t gofs[4];
    #pragma unroll
    for (int s = 0; s < 4; ++s) {
        const int rowg = s * 16 + rl;
        const int kfc  = sl ^ ((rowg >> 1) & 3);
        gofs[s] = (size_t)rowg * DD + kfc * 8;
    }

    f4 acc[3][2] = {};

    auto STAGE = [&](int buf, int kt) {
        unsigned char* base = lds + buf * 32768 + abase;
        #pragma unroll
        for (int s = 0; s < 4; ++s)
            gld16(sp2 + kt + gofs[s], base + s * 1024);
    };

    auto ldso = [&](int row, int kg) {
        return row * 64 + ((kg ^ ((row >> 1) & 3)) << 4);
    };

    auto COMPUTE = [&](int buf) {
        const unsigned char* base = lds + buf * 32768;
        const s8b ah0 = *(const s8b*)(base + 0*4096 + ldso(wr      + l15, l4));
        const s8b ah1 = *(const s8b*)(base + 0*4096 + ldso(wr + 16 + l15, l4));
        const s8b al0 = *(const s8b*)(base + 1*4096 + ldso(wr      + l15, l4));
        const s8b al1 = *(const s8b*)(base + 1*4096 + ldso(wr + 16 + l15, l4));
        #pragma unroll
        for (int s = 0; s < 3; ++s) {
            const s8b bh = *(const s8b*)(base + (2 + 2*s)*4096 + ldso(wc + l15, l4));
            const s8b bl = *(const s8b*)(base + (3 + 2*s)*4096 + ldso(wc + l15, l4));
            acc[s][0] = __builtin_amdgcn_mfma_f32_16x16x32_bf16(ah0, bh, acc[s][0], 0, 0, 0);
            acc[s][1] = __builtin_amdgcn_mfma_f32_16x16x32_bf16(ah1, bh, acc[s][1], 0, 0, 0);
            acc[s][0] = __builtin_amdgcn_mfma_f32_16x16x32_bf16(ah0, bl, acc[s][0], 0, 0, 0);
            acc[s][1] = __builtin_amdgcn_mfma_f32_16x16x32_bf16(ah1, bl, acc[s][1], 0, 0, 0);
            acc[s][0] = __builtin_amdgcn_mfma_f32_16x16x32_bf16(al0, bh, acc[s][0], 0, 0, 0);
            acc[s][1] = __builtin_amdgcn_mfma_f32_16x16x32_bf16(al1, bh, acc[s][1], 0, 0, 0);
        }
    };

    STAGE(0, 0);
    __syncthreads();
    int cur = 0;
    for (int it = 0; it < 16; ++it) {
        if (it < 15) STAGE(cur ^ 1, (it + 1) * 32);
        COMPUTE(cur);
        __syncthreads();
        cur ^= 1;
    }

    const int col = o0 + wc + l15;
    const float bva = ba[col], bvb = bb[col], bvc = bc[col];
    float asum = 0.f;
    #pragma unroll
    for (int ms = 0; ms < 2; ++ms) {
        const int row0 = m0 + wr + ms * 16 + l4 * 4;
        #pragma unroll
        for (int r = 0; r < 4; ++r) {
            const size_t o = (size_t)(row0 + r) * DD + col;
            float va = acc[0][ms][r] + bva;
            va = fminf(va, 0.f) - log1pf(__expf(-fabsf(va)));   // logsigmoid
            logA[o] = va;
            asum += va;
            Bf[o] = acc[1][ms][r] + bvb;
            Cf[o] = acc[2][ms][r] + bvc;
        }
    }

    asum += __shfl_xor(asum, 16);
    asum += __shfl_xor(asum, 32);
    if (wv < 4 && l4 == 0) csv[wc + l15] = asum;
    __syncthreads();
    if (wv >= 4 && l4 == 0) {
        const int blkc = (((bm >> 4) * 8 + bn) << 4) + (bm & 15);   // (b*8+h)*16+c
        csum[(size_t)blkc * DHD + wc + l15] = csv[wc + l15] + asum;
    }
}

// ---------------------------------------------------------------------------
// Kernel 2: scan + fused diag tile (unchanged from R12).
// ---------------------------------------------------------------------------
__global__ __launch_bounds__(256) void scan_diag(
    const float* __restrict__ logA, const float* __restrict__ Bf,
    const float* __restrict__ Cf, const float* __restrict__ csum,
    float* __restrict__ qf, float* __restrict__ kf,
    float* __restrict__ coff, float* __restrict__ out)
{
    __shared__ float part[4][DHD];
    __shared__ float smA[DHD][65];   // Cf stash [d][row]
    __shared__ float smB[DHD][65];   // Bf stash
    __shared__ float smC[DHD][65];   // Sloc stash

    const int blk = blockIdx.x;
    const int bh = blk >> 4, c = blk & 15;
    const int b = bh >> 3, h = bh & 7;
    const int t = threadIdx.x;
    const int d = t & 63, w = t >> 6;

    const size_t gbase = (size_t)(b * LL + c * QQ + w * 16) * DD + h * DHD + d;
    float lar[16];
    float ps = 0.f;
    #pragma unroll
    for (int i = 0; i < 16; ++i) {
        lar[i] = logA[gbase + (size_t)i * DD];
        ps += lar[i];
    }
    part[w][d] = ps;
    __syncthreads();

    const size_t cs0 = ((size_t)bh << 4) * DHD + d;
    float off = 0.f;
    for (int cc = 0; cc < c; ++cc) off += csum[cs0 + (size_t)cc * DHD];
    const float tot = part[0][d] + part[1][d] + part[2][d] + part[3][d];
    if (t < DHD) {
        coff[((size_t)bh * 17 + c) * DHD + t] = off;
        if (c == NCC - 1) coff[((size_t)bh * 17 + 16) * DHD + t] = off + tot;
    }

    float run = 0.f;
    for (int ww = 0; ww < 4; ++ww) if (ww < w) run += part[ww][d];

    const size_t hbase = ((size_t)bh * LL + c * QQ + w * 16) * DHD + d;
    #pragma unroll
    for (int i = 0; i < 16; ++i) {
        const size_t gi = gbase + (size_t)i * DD;
        const float cv = Cf[gi];
        const float bv = Bf[gi];
        qf[hbase + (size_t)i * DHD] = cv * __expf(run);       // exp(Sm1 - Eprev)
        run += lar[i];
        const int rloc = w * 16 + i;
        smC[d][rloc] = run;       // Sloc
        smA[d][rloc] = cv;        // C
        smB[d][rloc] = bv;        // B
        kf[hbase + (size_t)i * DHD] = bv * __expf(tot - run); // exp(E - S)
    }
    __syncthreads();

    // ---- diag tile compute ----
    const int q0 = ((t >> 4) & 15) << 2;
    const int k0 = (t & 15) << 2;

    float acc[4][4] = {};
    if (q0 + 3 >= k0) {
        #pragma unroll 2
        for (int dd = 0; dd < DHD; ++dd) {
            const float4 cq = *(const float4*)&smA[dd][q0];
            const float4 bk = *(const float4*)&smB[dd][k0];
            const float4 sk = *(const float4*)&smC[dd][k0];
            const float cqa[4] = {cq.x, cq.y, cq.z, cq.w};
            const float bka[4] = {bk.x, bk.y, bk.z, bk.w};
            const float ska[4] = {sk.x, sk.y, sk.z, sk.w};
            float s1a[4];
            #pragma unroll
            for (int i = 0; i < 4; ++i) {
                const int qi = q0 + i;
                s1a[i] = (qi == 0) ? 0.f : smC[dd][qi - 1];
            }
            #pragma unroll
            for (int i = 0; i < 4; ++i) {
                #pragma unroll
                for (int j = 0; j < 4; ++j) {
                    const int qi = q0 + i, kj = k0 + j;
                    const float wgt = (qi > kj) ? __expf(s1a[i] - ska[j])
                                                : ((qi == kj) ? 1.f : 0.f);
                    acc[i][j] += cqa[i] * wgt * bka[j];
                }
            }
        }
    }
    const size_t outrow0 = ((size_t)bh * LL + (size_t)c * QQ) * LL + (size_t)c * QQ;
    #pragma unroll
    for (int i = 0; i < 4; ++i)
        *(float4*)&out[outrow0 + (size_t)(q0 + i) * LL + k0] =
            make_float4(acc[i][0], acc[i][1], acc[i][2], acc[i][3]);
}

// ---------------------------------------------------------------------------
// Kernel 3: band v6 — kf fully in-register (no kf LDS, no per-tile barriers).
// Each lane gathers its own MFMA A-fragment rows (wr+l15, wr+16+l15) and
// k-chunk (ks*32+l4*8) of kf from global (L2-resident), applies dv=exp(..)
// and hi/lo split in registers, MFMAs against LDS-staged qf. Waves are fully
// independent across the n-loop -> deep per-wave pipelining.
// Block = (bh, m, half); n in [8*half, 8*half+8). LDS 16 KB (qf only).
// ---------------------------------------------------------------------------
__global__ __launch_bounds__(256) void band_row(
    const float* __restrict__ qf, const float* __restrict__ kf,
    const float* __restrict__ coff, float* __restrict__ out)
{
    __shared__ unsigned char lds[16384];
    unsigned char* const l_qh = lds;
    unsigned char* const l_ql = lds + 8192;

    const int half = blockIdx.x & 1;
    const int m    = (blockIdx.x >> 1) & 15;
    const int bh   = blockIdx.x >> 5;
    const int n0   = half << 3;

    const int t  = threadIdx.x;
    const int wv = t >> 6;
    const int ln = t & 63;
    const int l15 = ln & 15;
    const int l4  = ln >> 4;
    const int wr = (wv >> 1) << 5;           // k-side half (A operand)
    const int wc = (wv & 1) << 5;            // q-side half (B operand)

    const int srow = t >> 2;                 // 0..63
    const int skc  = (t & 3) << 4;           // 0/16/32/48
    const int slot0 = skc >> 3;

    const size_t cb = (size_t)bh * 17 * DHD;
    const size_t outbase = ((size_t)bh * LL + (size_t)m * QQ) * LL;

    // ---- zero tiles (n > m within range) ----
    for (int n = (m >= n0 ? m + 1 : n0); n < n0 + 8; ++n) {
        const size_t ob = outbase + (size_t)srow * LL + (size_t)n * QQ + skc;
        const float4 z = make_float4(0.f, 0.f, 0.f, 0.f);
        *(float4*)&out[ob + 0]  = z;
        *(float4*)&out[ob + 4]  = z;
        *(float4*)&out[ob + 8]  = z;
        *(float4*)&out[ob + 12] = z;
    }

    const int ne = (m < n0 + 8) ? m : (n0 + 8);   // offdiag n in [n0, ne)
    if (n0 >= ne) return;

    // ---- stage qf_m once (hi/lo split) ----
    {
        const size_t qb = ((size_t)bh * LL + (size_t)m * QQ + srow) * DHD + skc;
        float v[16];
        #pragma unroll
        for (int g = 0; g < 4; ++g) {
            const float4 x4 = *(const float4*)&qf[qb + g * 4];
            v[g*4+0]=x4.x; v[g*4+1]=x4.y; v[g*4+2]=x4.z; v[g*4+3]=x4.w;
        }
        unsigned short h[16], l[16];
        #pragma unroll
        for (int i = 0; i < 16; ++i) bf16split(v[i], h[i], l[i]);
        *(uint4*)(l_qh + slot0*1024 + srow*16) =
            make_uint4(pk2(h[0],h[1]), pk2(h[2],h[3]), pk2(h[4],h[5]), pk2(h[6],h[7]));
        *(uint4*)(l_qh + (slot0+1)*1024 + srow*16) =
            make_uint4(pk2(h[8],h[9]), pk2(h[10],h[11]), pk2(h[12],h[13]), pk2(h[14],h[15]));
        *(uint4*)(l_ql + slot0*1024 + srow*16) =
            make_uint4(pk2(l[0],l[1]), pk2(l[2],l[3]), pk2(l[4],l[5]), pk2(l[6],l[7]));
        *(uint4*)(l_ql + (slot0+1)*1024 + srow*16) =
            make_uint4(pk2(l[8],l[9]), pk2(l[10],l[11]), pk2(l[12],l[13]), pk2(l[14],l[15]));
    }
    __syncthreads();   // qf visible; only barrier in the kernel

    // ---- per-lane coff[m] for k positions ks*32 + l4*8 + j ----
    float cmv[16];
    #pragma unroll
    for (int ks = 0; ks < 2; ++ks) {
        const size_t o = cb + (size_t)m * DHD + ks * 32 + l4 * 8;
        const float4 a0 = *(const float4*)&coff[o + 0];
        const float4 a1 = *(const float4*)&coff[o + 4];
        cmv[ks*8+0]=a0.x; cmv[ks*8+1]=a0.y; cmv[ks*8+2]=a0.z; cmv[ks*8+3]=a0.w;
        cmv[ks*8+4]=a1.x; cmv[ks*8+5]=a1.y; cmv[ks*8+6]=a1.z; cmv[ks*8+7]=a1.w;
    }

    const int rA0 = wr + l15;
    const int rA1 = wr + 16 + l15;

    for (int n = n0; n < ne; ++n) {
        const size_t kb0 = ((size_t)bh * LL + (size_t)n * QQ + rA0) * DHD;
        const size_t kb1 = ((size_t)bh * LL + (size_t)n * QQ + rA1) * DHD;
        const size_t co  = cb + (size_t)(n + 1) * DHD;

        f4 acc[2][2] = {};   // [ms: k-half][ns: q-half]
        #pragma unroll
        for (int ks = 0; ks < 2; ++ks) {
            const int kcs = ks * 32 + l4 * 8;
            // dv = exp(coff[m] - coff[n+1]) for this lane's 8 k's
            float dv[8];
            {
                const float4 c0 = *(const float4*)&coff[co + kcs + 0];
                const float4 c1 = *(const float4*)&coff[co + kcs + 4];
                dv[0]=__expf(cmv[ks*8+0]-c0.x); dv[1]=__expf(cmv[ks*8+1]-c0.y);
                dv[2]=__expf(cmv[ks*8+2]-c0.z); dv[3]=__expf(cmv[ks*8+3]-c0.w);
                dv[4]=__expf(cmv[ks*8+4]-c1.x); dv[5]=__expf(cmv[ks*8+5]-c1.y);
                dv[6]=__expf(cmv[ks*8+6]-c1.z); dv[7]=__expf(cmv[ks*8+7]-c1.w);
            }
            // kf rows for this lane's fragment, scaled
            float va[8], vb[8];
            {
                const float4 x0 = *(const float4*)&kf[kb0 + kcs + 0];
                const float4 x1 = *(const float4*)&kf[kb0 + kcs + 4];
                va[0]=x0.x*dv[0]; va[1]=x0.y*dv[1]; va[2]=x0.z*dv[2]; va[3]=x0.w*dv[3];
                va[4]=x1.x*dv[4]; va[5]=x1.y*dv[5]; va[6]=x1.z*dv[6]; va[7]=x1.w*dv[7];
                const float4 y0 = *(const float4*)&kf[kb1 + kcs + 0];
                const float4 y1 = *(const float4*)&kf[kb1 + kcs + 4];
                vb[0]=y0.x*dv[0]; vb[1]=y0.y*dv[1]; vb[2]=y0.z*dv[2]; vb[3]=y0.w*dv[3];
                vb[4]=y1.x*dv[4]; vb[5]=y1.y*dv[5]; vb[6]=y1.z*dv[6]; vb[7]=y1.w*dv[7];
            }
            unsigned short ha[8], la[8], hb[8], lb[8];
            #pragma unroll
            for (int i = 0; i < 8; ++i) { bf16split(va[i], ha[i], la[i]); bf16split(vb[i], hb[i], lb[i]); }
            s8b kh0, kl0, kh1, kl1;
            #pragma unroll
            for (int i = 0; i < 8; ++i) {
                kh0[i] = (short)ha[i]; kl0[i] = (short)la[i];
                kh1[i] = (short)hb[i]; kl1[i] = (short)lb[i];
            }

            const int ka = (ks * 4 + l4) * 1024;
            const s8b qh0 = *(const s8b*)(l_qh + ka + (wc      + l15) * 16);
            const s8b qh1 = *(const s8b*)(l_qh + ka + (wc + 16 + l15) * 16);
            const s8b ql0 = *(const s8b*)(l_ql + ka + (wc      + l15) * 16);
            const s8b ql1 = *(const s8b*)(l_ql + ka + (wc + 16 + l15) * 16);

            acc[0][0] = __builtin_amdgcn_mfma_f32_16x16x32_bf16(kh0, qh0, acc[0][0], 0, 0, 0);
            acc[0][1] = __builtin_amdgcn_mfma_f32_16x16x32_bf16(kh0, qh1, acc[0][1], 0, 0, 0);
            acc[1][0] = __builtin_amdgcn_mfma_f32_16x16x32_bf16(kh1, qh0, acc[1][0], 0, 0, 0);
            acc[1][1] = __builtin_amdgcn_mfma_f32_16x16x32_bf16(kh1, qh1, acc[1][1], 0, 0, 0);
            acc[0][0] = __builtin_amdgcn_mfma_f32_16x16x32_bf16(kh0, ql0, acc[0][0], 0, 0, 0);
            acc[0][1] = __builtin_amdgcn_mfma_f32_16x16x32_bf16(kh0, ql1, acc[0][1], 0, 0, 0);
            acc[1][0] = __builtin_amdgcn_mfma_f32_16x16x32_bf16(kh1, ql0, acc[1][0], 0, 0, 0);
            acc[1][1] = __builtin_amdgcn_mfma_f32_16x16x32_bf16(kh1, ql1, acc[1][1], 0, 0, 0);
            acc[0][0] = __builtin_amdgcn_mfma_f32_16x16x32_bf16(kl0, qh0, acc[0][0], 0, 0, 0);
            acc[0][1] = __builtin_amdgcn_mfma_f32_16x16x32_bf16(kl0, qh1, acc[0][1], 0, 0, 0);
            acc[1][0] = __builtin_amdgcn_mfma_f32_16x16x32_bf16(kl1, qh0, acc[1][0], 0, 0, 0);
            acc[1][1] = __builtin_amdgcn_mfma_f32_16x16x32_bf16(kl1, qh1, acc[1][1], 0, 0, 0);
        }

        // lane holds T[q][k0..k0+3]: q = wc+ns*16+l15, k0 = wr+ms*16+l4*4
        #pragma unroll
        for (int ms = 0; ms < 2; ++ms) {
            #pragma unroll
            for (int ns = 0; ns < 2; ++ns) {
                const int q  = wc + ns * 16 + l15;
                const int k0 = wr + ms * 16 + l4 * 4;
                *(float4*)&out[outbase + (size_t)q * LL + (size_t)n * QQ + k0] =
                    make_float4(acc[ms][ns][0], acc[ms][ns][1], acc[ms][ns][2], acc[ms][ns][3]);
            }
        }
    }
}

// ---------------------------------------------------------------------------
extern "C" void kernel_launch(void* const* d_in, const int* in_sizes, int n_in,
                              void* d_out, int out_size, void* d_ws, size_t ws_size,
                              hipStream_t stream) {
    const float* x  = (const float*)d_in[0];
    const float* Wa = (const float*)d_in[1];
    const float* ba = (const float*)d_in[2];
    const float* Wb = (const float*)d_in[3];
    const float* bb = (const float*)d_in[4];
    const float* Wc = (const float*)d_in[5];
    const float* bc = (const float*)d_in[6];
    float* out = (float*)d_out;
    float* ws  = (float*)d_ws;

    const size_t NBLD = (size_t)BB * LL * DD;   // 1,048,576 floats
    float* logA = ws;
    float* Bf   = ws + 1 * NBLD;
    float* Cf   = ws + 2 * NBLD;
    // slot 3 holds the bf16 split staging arrays
    float* qf   = ws + 4 * NBLD;
    float* kf   = ws + 5 * NBLD;
    float* coff = ws + 6 * NBLD;                        // 16*17*64 floats
    float* csum = coff + (size_t)BB * HH * 17 * DHD;    // 256*64 floats

    unsigned short* xh  = (unsigned short*)(ws + 3 * NBLD);
    unsigned short* xl  = xh + 1048576;
    unsigned short* whp = xl + 1048576;    // 3 x 262144 (overlaps qf region,
    unsigned short* wlp = whp + 786432;    //  consumed before scan writes qf)

    convert_split<<<1792, 256, 0, stream>>>(x, Wa, Wb, Wc, xh, xl, whp, wlp);
    gemm3_fused<<<256, 512, 0, stream>>>(xh, xl, whp, wlp, ba, bb, bc, logA, Bf, Cf, csum);
    scan_diag<<<BB * HH * NCC, 256, 0, stream>>>(logA, Bf, Cf, csum, qf, kf, coff, out);
    band_row<<<BB * HH * NCC * 2, 256, 0, stream>>>(qf, kf, coff, out);
}

// Round 15
// 81.981 us; speedup vs baseline: 1.1105x; 1.1105x over previous
//
#include <hip/hip_runtime.h>
#include <math.h>

#define BB 2
#define LL 1024
#define DD 512
#define HH 8
#define DHD 64
#define QQ 64
#define NCC 16

typedef __attribute__((ext_vector_type(8))) short s8b;   // 8 bf16 (4 VGPRs)
typedef __attribute__((ext_vector_type(4))) float f4;    // 4 fp32 acc

__device__ __forceinline__ void bf16split(float f, unsigned short& h, unsigned short& l) {
    unsigned u  = __float_as_uint(f);
    unsigned hb = (u + 0x7FFFu + ((u >> 16) & 1u)) & 0xFFFF0000u;   // RTNE bf16
    float fh = __uint_as_float(hb);
    float fl = f - fh;
    unsigned ul = __float_as_uint(fl);
    unsigned lb = (ul + 0x7FFFu + ((ul >> 16) & 1u)) >> 16;
    h = (unsigned short)(hb >> 16);
    l = (unsigned short)lb;
}

__device__ __forceinline__ unsigned pk2(unsigned short a, unsigned short b) {
    return (unsigned)a | ((unsigned)b << 16);
}

// ---------------------------------------------------------------------------
// Kernel 1: fused 3-weight MFMA GEMM with IN-KERNEL bf16 hi/lo split
// (convert_split deleted). 256 blocks x 512 thr, double-buffered.
// Staging: wave w owns source w>>1 (0=x,1=Wa,2=Wb,3=Wc), rows (w&1)*32..+32.
// Lane: row roff=(w&1)*32+(ln>>1), 16 fp32 at k=(ln&1)*16 (coalesced 64 B),
// split in-reg, ds_write to the same swizzled layout the reader expects:
// slot = kg ^ ((row>>1)&3), arrays 0=xh,1=xl,2=wh0,3=wl0,4=wh1,5=wl1,6=wh2,7=wl2.
// Epilogue: bias + logsigmoid + csum column-sum (unchanged).
// ---------------------------------------------------------------------------
__global__ __launch_bounds__(512) void gemm3_fused(
    const float* __restrict__ x,
    const float* __restrict__ Wa, const float* __restrict__ ba,
    const float* __restrict__ Wb, const float* __restrict__ bb,
    const float* __restrict__ Wc, const float* __restrict__ bc,
    float* __restrict__ logA, float* __restrict__ Bf, float* __restrict__ Cf,
    float* __restrict__ csum)
{
    __shared__ unsigned char lds[65536];
    __shared__ float csv[64];

    const int bm = blockIdx.x >> 3;
    const int bn = blockIdx.x & 7;
    const int m0 = bm << 6, o0 = bn << 6;
    const int t = threadIdx.x, wv = t >> 6, ln = t & 63;
    const int l15 = ln & 15, l4 = ln >> 4;
    const int wr = (wv >> 2) << 5;      // 0 / 32
    const int wc = (wv & 3) << 4;       // 0 / 16 / 32 / 48

    // ---- staging assignment ----
    const int src_id = wv >> 1;                       // 0=x,1=Wa,2=Wb,3=Wc
    const float* srcp =
        (src_id == 0) ? x + (size_t)m0 * DD :
        ((src_id == 1) ? Wa : (src_id == 2) ? Wb : Wc) + (size_t)o0 * DD;
    const int roff = ((wv & 1) << 5) + (ln >> 1);     // local row 0..63
    const int ksh  = (ln & 1) << 4;                   // k sub-offset 0/16
    const int swz  = (roff >> 1) & 3;
    const int sA   = ((ksh >> 3) + 0) ^ swz;          // slot for k-chunk 0
    const int sB   = ((ksh >> 3) + 1) ^ swz;          // slot for k-chunk 1
    const size_t srow = (size_t)roff * DD + ksh;
    const int hiBase = (src_id * 2) * 4096 + roff * 64;

    f4 acc[3][2] = {};

    auto STAGE = [&](int buf, int kt) {
        const float* p = srcp + srow + kt;
        const float4 f0 = *(const float4*)(p + 0);
        const float4 f1 = *(const float4*)(p + 4);
        const float4 f2 = *(const float4*)(p + 8);
        const float4 f3 = *(const float4*)(p + 12);
        const float v[16] = {f0.x,f0.y,f0.z,f0.w, f1.x,f1.y,f1.z,f1.w,
                             f2.x,f2.y,f2.z,f2.w, f3.x,f3.y,f3.z,f3.w};
        unsigned short h[16], l[16];
        #pragma unroll
        for (int i = 0; i < 16; ++i) bf16split(v[i], h[i], l[i]);
        unsigned char* bh = lds + buf * 32768 + hiBase;
        unsigned char* bl = bh + 4096;
        *(uint4*)(bh + sA * 16) = make_uint4(pk2(h[0],h[1]),  pk2(h[2],h[3]),
                                             pk2(h[4],h[5]),  pk2(h[6],h[7]));
        *(uint4*)(bh + sB * 16) = make_uint4(pk2(h[8],h[9]),  pk2(h[10],h[11]),
                                             pk2(h[12],h[13]),pk2(h[14],h[15]));
        *(uint4*)(bl + sA * 16) = make_uint4(pk2(l[0],l[1]),  pk2(l[2],l[3]),
                                             pk2(l[4],l[5]),  pk2(l[6],l[7]));
        *(uint4*)(bl + sB * 16) = make_uint4(pk2(l[8],l[9]),  pk2(l[10],l[11]),
                                             pk2(l[12],l[13]),pk2(l[14],l[15]));
    };

    auto ldso = [&](int row, int kg) {
        return row * 64 + ((kg ^ ((row >> 1) & 3)) << 4);
    };

    auto COMPUTE = [&](int buf) {
        const unsigned char* base = lds + buf * 32768;
        const s8b ah0 = *(const s8b*)(base + 0*4096 + ldso(wr      + l15, l4));
        const s8b ah1 = *(const s8b*)(base + 0*4096 + ldso(wr + 16 + l15, l4));
        const s8b al0 = *(const s8b*)(base + 1*4096 + ldso(wr      + l15, l4));
        const s8b al1 = *(const s8b*)(base + 1*4096 + ldso(wr + 16 + l15, l4));
        #pragma unroll
        for (int s = 0; s < 3; ++s) {
            const s8b bh = *(const s8b*)(base + (2 + 2*s)*4096 + ldso(wc + l15, l4));
            const s8b bl = *(const s8b*)(base + (3 + 2*s)*4096 + ldso(wc + l15, l4));
            acc[s][0] = __builtin_amdgcn_mfma_f32_16x16x32_bf16(ah0, bh, acc[s][0], 0, 0, 0);
            acc[s][1] = __builtin_amdgcn_mfma_f32_16x16x32_bf16(ah1, bh, acc[s][1], 0, 0, 0);
            acc[s][0] = __builtin_amdgcn_mfma_f32_16x16x32_bf16(ah0, bl, acc[s][0], 0, 0, 0);
            acc[s][1] = __builtin_amdgcn_mfma_f32_16x16x32_bf16(ah1, bl, acc[s][1], 0, 0, 0);
            acc[s][0] = __builtin_amdgcn_mfma_f32_16x16x32_bf16(al0, bh, acc[s][0], 0, 0, 0);
            acc[s][1] = __builtin_amdgcn_mfma_f32_16x16x32_bf16(al1, bh, acc[s][1], 0, 0, 0);
        }
    };

    STAGE(0, 0);
    __syncthreads();
    int cur = 0;
    for (int it = 0; it < 16; ++it) {
        if (it < 15) STAGE(cur ^ 1, (it + 1) * 32);
        COMPUTE(cur);
        __syncthreads();
        cur ^= 1;
    }

    const int col = o0 + wc + l15;
    const float bva = ba[col], bvb = bb[col], bvc = bc[col];
    float asum = 0.f;
    #pragma unroll
    for (int ms = 0; ms < 2; ++ms) {
        const int row0 = m0 + wr + ms * 16 + l4 * 4;
        #pragma unroll
        for (int r = 0; r < 4; ++r) {
            const size_t o = (size_t)(row0 + r) * DD + col;
            float va = acc[0][ms][r] + bva;
            va = fminf(va, 0.f) - log1pf(__expf(-fabsf(va)));   // logsigmoid
            logA[o] = va;
            asum += va;
            Bf[o] = acc[1][ms][r] + bvb;
            Cf[o] = acc[2][ms][r] + bvc;
        }
    }

    asum += __shfl_xor(asum, 16);
    asum += __shfl_xor(asum, 32);
    if (wv < 4 && l4 == 0) csv[wc + l15] = asum;
    __syncthreads();
    if (wv >= 4 && l4 == 0) {
        const int blkc = (((bm >> 4) * 8 + bn) << 4) + (bm & 15);   // (b*8+h)*16+c
        csum[(size_t)blkc * DHD + wc + l15] = csv[wc + l15] + asum;
    }
}

// ---------------------------------------------------------------------------
// Kernel 2: scan + fused diag tile (unchanged from R12/R13).
// ---------------------------------------------------------------------------
__global__ __launch_bounds__(256) void scan_diag(
    const float* __restrict__ logA, const float* __restrict__ Bf,
    const float* __restrict__ Cf, const float* __restrict__ csum,
    float* __restrict__ qf, float* __restrict__ kf,
    float* __restrict__ coff, float* __restrict__ out)
{
    __shared__ float part[4][DHD];
    __shared__ float smA[DHD][65];   // Cf stash [d][row]
    __shared__ float smB[DHD][65];   // Bf stash
    __shared__ float smC[DHD][65];   // Sloc stash

    const int blk = blockIdx.x;
    const int bh = blk >> 4, c = blk & 15;
    const int b = bh >> 3, h = bh & 7;
    const int t = threadIdx.x;
    const int d = t & 63, w = t >> 6;

    const size_t gbase = (size_t)(b * LL + c * QQ + w * 16) * DD + h * DHD + d;
    float lar[16];
    float ps = 0.f;
    #pragma unroll
    for (int i = 0; i < 16; ++i) {
        lar[i] = logA[gbase + (size_t)i * DD];
        ps += lar[i];
    }
    part[w][d] = ps;
    __syncthreads();

    const size_t cs0 = ((size_t)bh << 4) * DHD + d;
    float off = 0.f;
    for (int cc = 0; cc < c; ++cc) off += csum[cs0 + (size_t)cc * DHD];
    const float tot = part[0][d] + part[1][d] + part[2][d] + part[3][d];
    if (t < DHD) {
        coff[((size_t)bh * 17 + c) * DHD + t] = off;
        if (c == NCC - 1) coff[((size_t)bh * 17 + 16) * DHD + t] = off + tot;
    }

    float run = 0.f;
    for (int ww = 0; ww < 4; ++ww) if (ww < w) run += part[ww][d];

    const size_t hbase = ((size_t)bh * LL + c * QQ + w * 16) * DHD + d;
    #pragma unroll
    for (int i = 0; i < 16; ++i) {
        const size_t gi = gbase + (size_t)i * DD;
        const float cv = Cf[gi];
        const float bv = Bf[gi];
        qf[hbase + (size_t)i * DHD] = cv * __expf(run);       // exp(Sm1 - Eprev)
        run += lar[i];
        const int rloc = w * 16 + i;
        smC[d][rloc] = run;       // Sloc
        smA[d][rloc] = cv;        // C
        smB[d][rloc] = bv;        // B
        kf[hbase + (size_t)i * DHD] = bv * __expf(tot - run); // exp(E - S)
    }
    __syncthreads();

    // ---- diag tile compute ----
    const int q0 = ((t >> 4) & 15) << 2;
    const int k0 = (t & 15) << 2;

    float acc[4][4] = {};
    if (q0 + 3 >= k0) {
        #pragma unroll 2
        for (int dd = 0; dd < DHD; ++dd) {
            const float4 cq = *(const float4*)&smA[dd][q0];
            const float4 bk = *(const float4*)&smB[dd][k0];
            const float4 sk = *(const float4*)&smC[dd][k0];
            const float cqa[4] = {cq.x, cq.y, cq.z, cq.w};
            const float bka[4] = {bk.x, bk.y, bk.z, bk.w};
            const float ska[4] = {sk.x, sk.y, sk.z, sk.w};
            float s1a[4];
            #pragma unroll
            for (int i = 0; i < 4; ++i) {
                const int qi = q0 + i;
                s1a[i] = (qi == 0) ? 0.f : smC[dd][qi - 1];
            }
            #pragma unroll
            for (int i = 0; i < 4; ++i) {
                #pragma unroll
                for (int j = 0; j < 4; ++j) {
                    const int qi = q0 + i, kj = k0 + j;
                    const float wgt = (qi > kj) ? __expf(s1a[i] - ska[j])
                                                : ((qi == kj) ? 1.f : 0.f);
                    acc[i][j] += cqa[i] * wgt * bka[j];
                }
            }
        }
    }
    const size_t outrow0 = ((size_t)bh * LL + (size_t)c * QQ) * LL + (size_t)c * QQ;
    #pragma unroll
    for (int i = 0; i < 4; ++i)
        *(float4*)&out[outrow0 + (size_t)(q0 + i) * LL + k0] =
            make_float4(acc[i][0], acc[i][1], acc[i][2], acc[i][3]);
}

// ---------------------------------------------------------------------------
// Kernel 3: band v5 (R13 exact). Block = (bh, m, half); n in [8h, 8h+8).
// qf staged once; kf double-buffered in LDS with T14 LOAD/WRITE split.
// ---------------------------------------------------------------------------
__global__ __launch_bounds__(256) void band_row(
    const float* __restrict__ qf, const float* __restrict__ kf,
    const float* __restrict__ coff, float* __restrict__ out)
{
    __shared__ unsigned char lds[49152];
    unsigned char* const l_qh = lds;
    unsigned char* const l_ql = lds + 8192;
    // k buffers: base 16384 + buf*16384, kh at +0, kl at +8192

    const int half = blockIdx.x & 1;
    const int m    = (blockIdx.x >> 1) & 15;
    const int bh   = blockIdx.x >> 5;
    const int n0   = half << 3;

    const int t  = threadIdx.x;
    const int wv = t >> 6;
    const int ln = t & 63;
    const int l15 = ln & 15;
    const int l4  = ln >> 4;
    const int wr = (wv >> 1) << 5;           // k-side half (A operand)
    const int wc = (wv & 1) << 5;            // q-side half (B operand)

    const int srow = t >> 2;                 // 0..63
    const int skc  = (t & 3) << 4;           // 0/16/32/48
    const int slot0 = skc >> 3;

    const size_t cb = (size_t)bh * 17 * DHD;
    const size_t outbase = ((size_t)bh * LL + (size_t)m * QQ) * LL;

    // ---- zero tiles (n > m within range) ----
    for (int n = (m >= n0 ? m + 1 : n0); n < n0 + 8; ++n) {
        const size_t ob = outbase + (size_t)srow * LL + (size_t)n * QQ + skc;
        const float4 z = make_float4(0.f, 0.f, 0.f, 0.f);
        *(float4*)&out[ob + 0]  = z;
        *(float4*)&out[ob + 4]  = z;
        *(float4*)&out[ob + 8]  = z;
        *(float4*)&out[ob + 12] = z;
    }

    const int ne = (m < n0 + 8) ? m : (n0 + 8);   // offdiag n in [n0, ne)
    if (n0 >= ne) return;

    // ---- coff[m] slice ----
    float cm[16];
    #pragma unroll
    for (int g = 0; g < 4; ++g) {
        const float4 a = *(const float4*)&coff[cb + (size_t)m * DHD + skc + g * 4];
        cm[g*4+0]=a.x; cm[g*4+1]=a.y; cm[g*4+2]=a.z; cm[g*4+3]=a.w;
    }

    // ---- stage qf_m once (hi/lo split) ----
    {
        const size_t qb = ((size_t)bh * LL + (size_t)m * QQ + srow) * DHD + skc;
        float v[16];
        #pragma unroll
        for (int g = 0; g < 4; ++g) {
            const float4 x4 = *(const float4*)&qf[qb + g * 4];
            v[g*4+0]=x4.x; v[g*4+1]=x4.y; v[g*4+2]=x4.z; v[g*4+3]=x4.w;
        }
        unsigned short h[16], l[16];
        #pragma unroll
        for (int i = 0; i < 16; ++i) bf16split(v[i], h[i], l[i]);
        *(uint4*)(l_qh + slot0*1024 + srow*16) =
            make_uint4(pk2(h[0],h[1]), pk2(h[2],h[3]), pk2(h[4],h[5]), pk2(h[6],h[7]));
        *(uint4*)(l_qh + (slot0+1)*1024 + srow*16) =
            make_uint4(pk2(h[8],h[9]), pk2(h[10],h[11]), pk2(h[12],h[13]), pk2(h[14],h[15]));
        *(uint4*)(l_ql + slot0*1024 + srow*16) =
            make_uint4(pk2(l[0],l[1]), pk2(l[2],l[3]), pk2(l[4],l[5]), pk2(l[6],l[7]));
        *(uint4*)(l_ql + (slot0+1)*1024 + srow*16) =
            make_uint4(pk2(l[8],l[9]), pk2(l[10],l[11]), pk2(l[12],l[13]), pk2(l[14],l[15]));
    }

    // ---- T14 split staging: LOAD (global->reg) / WRITE (exp+split+LDS) ----
    auto LOAD_K = [&](int n, float* vk, float* vc) {
        const size_t kb = ((size_t)bh * LL + (size_t)n * QQ + srow) * DHD + skc;
        #pragma unroll
        for (int g = 0; g < 4; ++g) {
            const float4 x4 = *(const float4*)&kf[kb + g * 4];
            vk[g*4+0]=x4.x; vk[g*4+1]=x4.y; vk[g*4+2]=x4.z; vk[g*4+3]=x4.w;
            const float4 c4 = *(const float4*)&coff[cb + (size_t)(n + 1) * DHD + skc + g * 4];
            vc[g*4+0]=c4.x; vc[g*4+1]=c4.y; vc[g*4+2]=c4.z; vc[g*4+3]=c4.w;
        }
    };

    auto WRITE_K = [&](int buf, const float* vk, const float* vc) {
        unsigned char* const kh_b = lds + 16384 + buf * 16384;
        unsigned char* const kl_b = kh_b + 8192;
        float v[16];
        #pragma unroll
        for (int i = 0; i < 16; ++i)
            v[i] = vk[i] * __expf(cm[i] - vc[i]);
        unsigned short h[16], l[16];
        #pragma unroll
        for (int i = 0; i < 16; ++i) bf16split(v[i], h[i], l[i]);
        *(uint4*)(kh_b + slot0*1024 + srow*16) =
            make_uint4(pk2(h[0],h[1]), pk2(h[2],h[3]), pk2(h[4],h[5]), pk2(h[6],h[7]));
        *(uint4*)(kh_b + (slot0+1)*1024 + srow*16) =
            make_uint4(pk2(h[8],h[9]), pk2(h[10],h[11]), pk2(h[12],h[13]), pk2(h[14],h[15]));
        *(uint4*)(kl_b + slot0*1024 + srow*16) =
            make_uint4(pk2(l[0],l[1]), pk2(l[2],l[3]), pk2(l[4],l[5]), pk2(l[6],l[7]));
        *(uint4*)(kl_b + (slot0+1)*1024 + srow*16) =
            make_uint4(pk2(l[8],l[9]), pk2(l[10],l[11]), pk2(l[12],l[13]), pk2(l[14],l[15]));
    };

    {
        float pk0[16], pc0[16];
        LOAD_K(n0, pk0, pc0);
        WRITE_K(0, pk0, pc0);
    }
    __syncthreads();

    int cur = 0;
    for (int n = n0; n < ne; ++n) {
        float nk[16], nc[16];
        const bool pre = (n + 1 < ne);
        if (pre) LOAD_K(n + 1, nk, nc);          // loads issue; no use yet

        const unsigned char* const kh_b = lds + 16384 + cur * 16384;
        const unsigned char* const kl_b = kh_b + 8192;

        f4 acc[2][2] = {};   // MFMA overlaps the in-flight loads
        #pragma unroll
        for (int ks = 0; ks < 2; ++ks) {
            const int ka = (ks * 4 + l4) * 1024;
            const s8b kh0 = *(const s8b*)(kh_b + ka + (wr      + l15) * 16);
            const s8b kh1 = *(const s8b*)(kh_b + ka + (wr + 16 + l15) * 16);
            const s8b kl0 = *(const s8b*)(kl_b + ka + (wr      + l15) * 16);
            const s8b kl1 = *(const s8b*)(kl_b + ka + (wr + 16 + l15) * 16);
            const s8b qh0 = *(const s8b*)(l_qh + ka + (wc      + l15) * 16);
            const s8b qh1 = *(const s8b*)(l_qh + ka + (wc + 16 + l15) * 16);
            const s8b ql0 = *(const s8b*)(l_ql + ka + (wc      + l15) * 16);
            const s8b ql1 = *(const s8b*)(l_ql + ka + (wc + 16 + l15) * 16);

            acc[0][0] = __builtin_amdgcn_mfma_f32_16x16x32_bf16(kh0, qh0, acc[0][0], 0, 0, 0);
            acc[0][1] = __builtin_amdgcn_mfma_f32_16x16x32_bf16(kh0, qh1, acc[0][1], 0, 0, 0);
            acc[1][0] = __builtin_amdgcn_mfma_f32_16x16x32_bf16(kh1, qh0, acc[1][0], 0, 0, 0);
            acc[1][1] = __builtin_amdgcn_mfma_f32_16x16x32_bf16(kh1, qh1, acc[1][1], 0, 0, 0);
            acc[0][0] = __builtin_amdgcn_mfma_f32_16x16x32_bf16(kh0, ql0, acc[0][0], 0, 0, 0);
            acc[0][1] = __builtin_amdgcn_mfma_f32_16x16x32_bf16(kh0, ql1, acc[0][1], 0, 0, 0);
            acc[1][0] = __builtin_amdgcn_mfma_f32_16x16x32_bf16(kh1, ql0, acc[1][0], 0, 0, 0);
            acc[1][1] = __builtin_amdgcn_mfma_f32_16x16x32_bf16(kh1, ql1, acc[1][1], 0, 0, 0);
            acc[0][0] = __builtin_amdgcn_mfma_f32_16x16x32_bf16(kl0, qh0, acc[0][0], 0, 0, 0);
            acc[0][1] = __builtin_amdgcn_mfma_f32_16x16x32_bf16(kl0, qh1, acc[0][1], 0, 0, 0);
            acc[1][0] = __builtin_amdgcn_mfma_f32_16x16x32_bf16(kl1, qh0, acc[1][0], 0, 0, 0);
            acc[1][1] = __builtin_amdgcn_mfma_f32_16x16x32_bf16(kl1, qh1, acc[1][1], 0, 0, 0);
        }

        // lane holds T[q][k0..k0+3]: q = wc+ns*16+l15, k0 = wr+ms*16+l4*4
        #pragma unroll
        for (int ms = 0; ms < 2; ++ms) {
            #pragma unroll
            for (int ns = 0; ns < 2; ++ns) {
                const int q  = wc + ns * 16 + l15;
                const int k0 = wr + ms * 16 + l4 * 4;
                *(float4*)&out[outbase + (size_t)q * LL + (size_t)n * QQ + k0] =
                    make_float4(acc[ms][ns][0], acc[ms][ns][1], acc[ms][ns][2], acc[ms][ns][3]);
            }
        }

        if (pre) WRITE_K(cur ^ 1, nk, nc);       // vmcnt waits land here

        __syncthreads();   // staged n+1 visible; buf cur free for overwrite
        cur ^= 1;
    }
}

// ---------------------------------------------------------------------------
extern "C" void kernel_launch(void* const* d_in, const int* in_sizes, int n_in,
                              void* d_out, int out_size, void* d_ws, size_t ws_size,
                              hipStream_t stream) {
    const float* x  = (const float*)d_in[0];
    const float* Wa = (const float*)d_in[1];
    const float* ba = (const float*)d_in[2];
    const float* Wb = (const float*)d_in[3];
    const float* bb = (const float*)d_in[4];
    const float* Wc = (const float*)d_in[5];
    const float* bc = (const float*)d_in[6];
    float* out = (float*)d_out;
    float* ws  = (float*)d_ws;

    const size_t NBLD = (size_t)BB * LL * DD;   // 1,048,576 floats
    float* logA = ws;
    float* Bf   = ws + 1 * NBLD;
    float* Cf   = ws + 2 * NBLD;
    float* qf   = ws + 4 * NBLD;
    float* kf   = ws + 5 * NBLD;
    float* coff = ws + 6 * NBLD;                        // 16*17*64 floats
    float* csum = coff + (size_t)BB * HH * 17 * DHD;    // 256*64 floats

    gemm3_fused<<<256, 512, 0, stream>>>(x, Wa, ba, Wb, bb, Wc, bc, logA, Bf, Cf, csum);
    scan_diag<<<BB * HH * NCC, 256, 0, stream>>>(logA, Bf, Cf, csum, qf, kf, coff, out);
    band_row<<<BB * HH * NCC * 2, 256, 0, stream>>>(qf, kf, coff, out);
}

// Round 16
// 76.940 us; speedup vs baseline: 1.1832x; 1.0655x over previous
//
#include <hip/hip_runtime.h>
#include <math.h>

#define BB 2
#define LL 1024
#define DD 512
#define HH 8
#define DHD 64
#define QQ 64
#define NCC 16

typedef __attribute__((ext_vector_type(8))) short s8b;   // 8 bf16 (4 VGPRs)
typedef __attribute__((ext_vector_type(4))) float f4;    // 4 fp32 acc

__device__ __forceinline__ void bf16split(float f, unsigned short& h, unsigned short& l) {
    unsigned u  = __float_as_uint(f);
    unsigned hb = (u + 0x7FFFu + ((u >> 16) & 1u)) & 0xFFFF0000u;   // RTNE bf16
    float fh = __uint_as_float(hb);
    float fl = f - fh;
    unsigned ul = __float_as_uint(fl);
    unsigned lb = (ul + 0x7FFFu + ((ul >> 16) & 1u)) >> 16;
    h = (unsigned short)(hb >> 16);
    l = (unsigned short)lb;
}

__device__ __forceinline__ unsigned pk2(unsigned short a, unsigned short b) {
    return (unsigned)a | ((unsigned)b << 16);
}

// ---------------------------------------------------------------------------
// Kernel 1: fused 3-weight MFMA GEMM with in-kernel bf16 hi/lo split
// (unchanged from R15).
// ---------------------------------------------------------------------------
__global__ __launch_bounds__(512) void gemm3_fused(
    const float* __restrict__ x,
    const float* __restrict__ Wa, const float* __restrict__ ba,
    const float* __restrict__ Wb, const float* __restrict__ bb,
    const float* __restrict__ Wc, const float* __restrict__ bc,
    float* __restrict__ logA, float* __restrict__ Bf, float* __restrict__ Cf,
    float* __restrict__ csum)
{
    __shared__ unsigned char lds[65536];
    __shared__ float csv[64];

    const int bm = blockIdx.x >> 3;
    const int bn = blockIdx.x & 7;
    const int m0 = bm << 6, o0 = bn << 6;
    const int t = threadIdx.x, wv = t >> 6, ln = t & 63;
    const int l15 = ln & 15, l4 = ln >> 4;
    const int wr = (wv >> 2) << 5;      // 0 / 32
    const int wc = (wv & 3) << 4;       // 0 / 16 / 32 / 48

    const int src_id = wv >> 1;                       // 0=x,1=Wa,2=Wb,3=Wc
    const float* srcp =
        (src_id == 0) ? x + (size_t)m0 * DD :
        ((src_id == 1) ? Wa : (src_id == 2) ? Wb : Wc) + (size_t)o0 * DD;
    const int roff = ((wv & 1) << 5) + (ln >> 1);     // local row 0..63
    const int ksh  = (ln & 1) << 4;                   // k sub-offset 0/16
    const int swz  = (roff >> 1) & 3;
    const int sA   = ((ksh >> 3) + 0) ^ swz;
    const int sB   = ((ksh >> 3) + 1) ^ swz;
    const size_t srow = (size_t)roff * DD + ksh;
    const int hiBase = (src_id * 2) * 4096 + roff * 64;

    f4 acc[3][2] = {};

    auto STAGE = [&](int buf, int kt) {
        const float* p = srcp + srow + kt;
        const float4 f0 = *(const float4*)(p + 0);
        const float4 f1 = *(const float4*)(p + 4);
        const float4 f2 = *(const float4*)(p + 8);
        const float4 f3 = *(const float4*)(p + 12);
        const float v[16] = {f0.x,f0.y,f0.z,f0.w, f1.x,f1.y,f1.z,f1.w,
                             f2.x,f2.y,f2.z,f2.w, f3.x,f3.y,f3.z,f3.w};
        unsigned short h[16], l[16];
        #pragma unroll
        for (int i = 0; i < 16; ++i) bf16split(v[i], h[i], l[i]);
        unsigned char* bh = lds + buf * 32768 + hiBase;
        unsigned char* bl = bh + 4096;
        *(uint4*)(bh + sA * 16) = make_uint4(pk2(h[0],h[1]),  pk2(h[2],h[3]),
                                             pk2(h[4],h[5]),  pk2(h[6],h[7]));
        *(uint4*)(bh + sB * 16) = make_uint4(pk2(h[8],h[9]),  pk2(h[10],h[11]),
                                             pk2(h[12],h[13]),pk2(h[14],h[15]));
        *(uint4*)(bl + sA * 16) = make_uint4(pk2(l[0],l[1]),  pk2(l[2],l[3]),
                                             pk2(l[4],l[5]),  pk2(l[6],l[7]));
        *(uint4*)(bl + sB * 16) = make_uint4(pk2(l[8],l[9]),  pk2(l[10],l[11]),
                                             pk2(l[12],l[13]),pk2(l[14],l[15]));
    };

    auto ldso = [&](int row, int kg) {
        return row * 64 + ((kg ^ ((row >> 1) & 3)) << 4);
    };

    auto COMPUTE = [&](int buf) {
        const unsigned char* base = lds + buf * 32768;
        const s8b ah0 = *(const s8b*)(base + 0*4096 + ldso(wr      + l15, l4));
        const s8b ah1 = *(const s8b*)(base + 0*4096 + ldso(wr + 16 + l15, l4));
        const s8b al0 = *(const s8b*)(base + 1*4096 + ldso(wr      + l15, l4));
        const s8b al1 = *(const s8b*)(base + 1*4096 + ldso(wr + 16 + l15, l4));
        #pragma unroll
        for (int s = 0; s < 3; ++s) {
            const s8b bh = *(const s8b*)(base + (2 + 2*s)*4096 + ldso(wc + l15, l4));
            const s8b bl = *(const s8b*)(base + (3 + 2*s)*4096 + ldso(wc + l15, l4));
            acc[s][0] = __builtin_amdgcn_mfma_f32_16x16x32_bf16(ah0, bh, acc[s][0], 0, 0, 0);
            acc[s][1] = __builtin_amdgcn_mfma_f32_16x16x32_bf16(ah1, bh, acc[s][1], 0, 0, 0);
            acc[s][0] = __builtin_amdgcn_mfma_f32_16x16x32_bf16(ah0, bl, acc[s][0], 0, 0, 0);
            acc[s][1] = __builtin_amdgcn_mfma_f32_16x16x32_bf16(ah1, bl, acc[s][1], 0, 0, 0);
            acc[s][0] = __builtin_amdgcn_mfma_f32_16x16x32_bf16(al0, bh, acc[s][0], 0, 0, 0);
            acc[s][1] = __builtin_amdgcn_mfma_f32_16x16x32_bf16(al1, bh, acc[s][1], 0, 0, 0);
        }
    };

    STAGE(0, 0);
    __syncthreads();
    int cur = 0;
    for (int it = 0; it < 16; ++it) {
        if (it < 15) STAGE(cur ^ 1, (it + 1) * 32);
        COMPUTE(cur);
        __syncthreads();
        cur ^= 1;
    }

    const int col = o0 + wc + l15;
    const float bva = ba[col], bvb = bb[col], bvc = bc[col];
    float asum = 0.f;
    #pragma unroll
    for (int ms = 0; ms < 2; ++ms) {
        const int row0 = m0 + wr + ms * 16 + l4 * 4;
        #pragma unroll
        for (int r = 0; r < 4; ++r) {
            const size_t o = (size_t)(row0 + r) * DD + col;
            float va = acc[0][ms][r] + bva;
            va = fminf(va, 0.f) - log1pf(__expf(-fabsf(va)));   // logsigmoid
            logA[o] = va;
            asum += va;
            Bf[o] = acc[1][ms][r] + bvb;
            Cf[o] = acc[2][ms][r] + bvc;
        }
    }

    asum += __shfl_xor(asum, 16);
    asum += __shfl_xor(asum, 32);
    if (wv < 4 && l4 == 0) csv[wc + l15] = asum;
    __syncthreads();
    if (wv >= 4 && l4 == 0) {
        const int blkc = (((bm >> 4) * 8 + bn) << 4) + (bm & 15);   // (b*8+h)*16+c
        csum[(size_t)blkc * DHD + wc + l15] = csv[wc + l15] + asum;
    }
}

// ---------------------------------------------------------------------------
// Kernel 2: scan + fused diag tile + NEW: strict-upper zero-fill tail
// (offloaded from band_row; store-only, no barrier interaction).
// ---------------------------------------------------------------------------
__global__ __launch_bounds__(256) void scan_diag(
    const float* __restrict__ logA, const float* __restrict__ Bf,
    const float* __restrict__ Cf, const float* __restrict__ csum,
    float* __restrict__ qf, float* __restrict__ kf,
    float* __restrict__ coff, float* __restrict__ out)
{
    __shared__ float part[4][DHD];
    __shared__ float smA[DHD][65];   // Cf stash [d][row]
    __shared__ float smB[DHD][65];   // Bf stash
    __shared__ float smC[DHD][65];   // Sloc stash

    const int blk = blockIdx.x;
    const int bh = blk >> 4, c = blk & 15;
    const int b = bh >> 3, h = bh & 7;
    const int t = threadIdx.x;
    const int d = t & 63, w = t >> 6;

    const size_t gbase = (size_t)(b * LL + c * QQ + w * 16) * DD + h * DHD + d;
    float lar[16];
    float ps = 0.f;
    #pragma unroll
    for (int i = 0; i < 16; ++i) {
        lar[i] = logA[gbase + (size_t)i * DD];
        ps += lar[i];
    }
    part[w][d] = ps;
    __syncthreads();

    const size_t cs0 = ((size_t)bh << 4) * DHD + d;
    float off = 0.f;
    for (int cc = 0; cc < c; ++cc) off += csum[cs0 + (size_t)cc * DHD];
    const float tot = part[0][d] + part[1][d] + part[2][d] + part[3][d];
    if (t < DHD) {
        coff[((size_t)bh * 17 + c) * DHD + t] = off;
        if (c == NCC - 1) coff[((size_t)bh * 17 + 16) * DHD + t] = off + tot;
    }

    float run = 0.f;
    for (int ww = 0; ww < 4; ++ww) if (ww < w) run += part[ww][d];

    const size_t hbase = ((size_t)bh * LL + c * QQ + w * 16) * DHD + d;
    #pragma unroll
    for (int i = 0; i < 16; ++i) {
        const size_t gi = gbase + (size_t)i * DD;
        const float cv = Cf[gi];
        const float bv = Bf[gi];
        qf[hbase + (size_t)i * DHD] = cv * __expf(run);       // exp(Sm1 - Eprev)
        run += lar[i];
        const int rloc = w * 16 + i;
        smC[d][rloc] = run;       // Sloc
        smA[d][rloc] = cv;        // C
        smB[d][rloc] = bv;        // B
        kf[hbase + (size_t)i * DHD] = bv * __expf(tot - run); // exp(E - S)
    }
    __syncthreads();

    // ---- diag tile compute ----
    const int q0 = ((t >> 4) & 15) << 2;
    const int k0 = (t & 15) << 2;

    float acc[4][4] = {};
    if (q0 + 3 >= k0) {
        #pragma unroll 2
        for (int dd = 0; dd < DHD; ++dd) {
            const float4 cq = *(const float4*)&smA[dd][q0];
            const float4 bk = *(const float4*)&smB[dd][k0];
            const float4 sk = *(const float4*)&smC[dd][k0];
            const float cqa[4] = {cq.x, cq.y, cq.z, cq.w};
            const float bka[4] = {bk.x, bk.y, bk.z, bk.w};
            const float ska[4] = {sk.x, sk.y, sk.z, sk.w};
            float s1a[4];
            #pragma unroll
            for (int i = 0; i < 4; ++i) {
                const int qi = q0 + i;
                s1a[i] = (qi == 0) ? 0.f : smC[dd][qi - 1];
            }
            #pragma unroll
            for (int i = 0; i < 4; ++i) {
                #pragma unroll
                for (int j = 0; j < 4; ++j) {
                    const int qi = q0 + i, kj = k0 + j;
                    const float wgt = (qi > kj) ? __expf(s1a[i] - ska[j])
                                                : ((qi == kj) ? 1.f : 0.f);
                    acc[i][j] += cqa[i] * wgt * bka[j];
                }
            }
        }
    }
    const size_t outrow0 = ((size_t)bh * LL + (size_t)c * QQ) * LL + (size_t)c * QQ;
    #pragma unroll
    for (int i = 0; i < 4; ++i)
        *(float4*)&out[outrow0 + (size_t)(q0 + i) * LL + k0] =
            make_float4(acc[i][0], acc[i][1], acc[i][2], acc[i][3]);

    // ---- strict-upper zero-fill (1920 tiles spread over 256 blocks) ----
    for (int z = blk; z < BB * HH * 120; z += 256) {
        const int zbh = z / 120;
        const int idx = z - zbh * 120;
        int a = (int)((1.0f + sqrtf(1.0f + 8.0f * (float)idx)) * 0.5f);
        if (a * (a - 1) / 2 > idx) --a;
        else if ((a + 1) * a / 2 <= idx) ++a;
        const int zm = idx - a * (a - 1) / 2;   // row-chunk
        const int zn = a;                       // col-chunk, zn > zm
        const size_t zb = ((size_t)zbh * LL + (size_t)zm * QQ) * LL + (size_t)zn * QQ;
        const float4 zz = make_float4(0.f, 0.f, 0.f, 0.f);
        #pragma unroll
        for (int r = 0; r < 4; ++r) {
            const int fi = t + (r << 8);        // float4 idx 0..1023
            const int row = fi >> 4;
            const int col = (fi & 15) << 2;
            *(float4*)&out[zb + (size_t)row * LL + col] = zz;
        }
    }
}

// ---------------------------------------------------------------------------
// Kernel 3: band v7 = R13/R15 body with the zero-fill REMOVED (offdiag only).
// Block = (bh, m, half); n in [8h, 8h+8). qf staged once; kf dbuf + T14 split.
// ---------------------------------------------------------------------------
__global__ __launch_bounds__(256) void band_row(
    const float* __restrict__ qf, const float* __restrict__ kf,
    const float* __restrict__ coff, float* __restrict__ out)
{
    __shared__ unsigned char lds[49152];
    unsigned char* const l_qh = lds;
    unsigned char* const l_ql = lds + 8192;
    // k buffers: base 16384 + buf*16384, kh at +0, kl at +8192

    const int half = blockIdx.x & 1;
    const int m    = (blockIdx.x >> 1) & 15;
    const int bh   = blockIdx.x >> 5;
    const int n0   = half << 3;

    const int t  = threadIdx.x;
    const int wv = t >> 6;
    const int ln = t & 63;
    const int l15 = ln & 15;
    const int l4  = ln >> 4;
    const int wr = (wv >> 1) << 5;           // k-side half (A operand)
    const int wc = (wv & 1) << 5;            // q-side half (B operand)

    const int srow = t >> 2;                 // 0..63
    const int skc  = (t & 3) << 4;           // 0/16/32/48
    const int slot0 = skc >> 3;

    const size_t cb = (size_t)bh * 17 * DHD;
    const size_t outbase = ((size_t)bh * LL + (size_t)m * QQ) * LL;

    const int ne = (m < n0 + 8) ? m : (n0 + 8);   // offdiag n in [n0, ne)
    if (n0 >= ne) return;

    // ---- coff[m] slice ----
    float cm[16];
    #pragma unroll
    for (int g = 0; g < 4; ++g) {
        const float4 a = *(const float4*)&coff[cb + (size_t)m * DHD + skc + g * 4];
        cm[g*4+0]=a.x; cm[g*4+1]=a.y; cm[g*4+2]=a.z; cm[g*4+3]=a.w;
    }

    // ---- stage qf_m once (hi/lo split) ----
    {
        const size_t qb = ((size_t)bh * LL + (size_t)m * QQ + srow) * DHD + skc;
        float v[16];
        #pragma unroll
        for (int g = 0; g < 4; ++g) {
            const float4 x4 = *(const float4*)&qf[qb + g * 4];
            v[g*4+0]=x4.x; v[g*4+1]=x4.y; v[g*4+2]=x4.z; v[g*4+3]=x4.w;
        }
        unsigned short h[16], l[16];
        #pragma unroll
        for (int i = 0; i < 16; ++i) bf16split(v[i], h[i], l[i]);
        *(uint4*)(l_qh + slot0*1024 + srow*16) =
            make_uint4(pk2(h[0],h[1]), pk2(h[2],h[3]), pk2(h[4],h[5]), pk2(h[6],h[7]));
        *(uint4*)(l_qh + (slot0+1)*1024 + srow*16) =
            make_uint4(pk2(h[8],h[9]), pk2(h[10],h[11]), pk2(h[12],h[13]), pk2(h[14],h[15]));
        *(uint4*)(l_ql + slot0*1024 + srow*16) =
            make_uint4(pk2(l[0],l[1]), pk2(l[2],l[3]), pk2(l[4],l[5]), pk2(l[6],l[7]));
        *(uint4*)(l_ql + (slot0+1)*1024 + srow*16) =
            make_uint4(pk2(l[8],l[9]), pk2(l[10],l[11]), pk2(l[12],l[13]), pk2(l[14],l[15]));
    }

    // ---- T14 split staging: LOAD (global->reg) / WRITE (exp+split+LDS) ----
    auto LOAD_K = [&](int n, float* vk, float* vc) {
        const size_t kb = ((size_t)bh * LL + (size_t)n * QQ + srow) * DHD + skc;
        #pragma unroll
        for (int g = 0; g < 4; ++g) {
            const float4 x4 = *(const float4*)&kf[kb + g * 4];
            vk[g*4+0]=x4.x; vk[g*4+1]=x4.y; vk[g*4+2]=x4.z; vk[g*4+3]=x4.w;
            const float4 c4 = *(const float4*)&coff[cb + (size_t)(n + 1) * DHD + skc + g * 4];
            vc[g*4+0]=c4.x; vc[g*4+1]=c4.y; vc[g*4+2]=c4.z; vc[g*4+3]=c4.w;
        }
    };

    auto WRITE_K = [&](int buf, const float* vk, const float* vc) {
        unsigned char* const kh_b = lds + 16384 + buf * 16384;
        unsigned char* const kl_b = kh_b + 8192;
        float v[16];
        #pragma unroll
        for (int i = 0; i < 16; ++i)
            v[i] = vk[i] * __expf(cm[i] - vc[i]);
        unsigned short h[16], l[16];
        #pragma unroll
        for (int i = 0; i < 16; ++i) bf16split(v[i], h[i], l[i]);
        *(uint4*)(kh_b + slot0*1024 + srow*16) =
            make_uint4(pk2(h[0],h[1]), pk2(h[2],h[3]), pk2(h[4],h[5]), pk2(h[6],h[7]));
        *(uint4*)(kh_b + (slot0+1)*1024 + srow*16) =
            make_uint4(pk2(h[8],h[9]), pk2(h[10],h[11]), pk2(h[12],h[13]), pk2(h[14],h[15]));
        *(uint4*)(kl_b + slot0*1024 + srow*16) =
            make_uint4(pk2(l[0],l[1]), pk2(l[2],l[3]), pk2(l[4],l[5]), pk2(l[6],l[7]));
        *(uint4*)(kl_b + (slot0+1)*1024 + srow*16) =
            make_uint4(pk2(l[8],l[9]), pk2(l[10],l[11]), pk2(l[12],l[13]), pk2(l[14],l[15]));
    };

    {
        float pk0[16], pc0[16];
        LOAD_K(n0, pk0, pc0);
        WRITE_K(0, pk0, pc0);
    }
    __syncthreads();

    int cur = 0;
    for (int n = n0; n < ne; ++n) {
        float nk[16], nc[16];
        const bool pre = (n + 1 < ne);
        if (pre) LOAD_K(n + 1, nk, nc);          // loads issue; no use yet

        const unsigned char* const kh_b = lds + 16384 + cur * 16384;
        const unsigned char* const kl_b = kh_b + 8192;

        f4 acc[2][2] = {};   // MFMA overlaps the in-flight loads
        #pragma unroll
        for (int ks = 0; ks < 2; ++ks) {
            const int ka = (ks * 4 + l4) * 1024;
            const s8b kh0 = *(const s8b*)(kh_b + ka + (wr      + l15) * 16);
            const s8b kh1 = *(const s8b*)(kh_b + ka + (wr + 16 + l15) * 16);
            const s8b kl0 = *(const s8b*)(kl_b + ka + (wr      + l15) * 16);
            const s8b kl1 = *(const s8b*)(kl_b + ka + (wr + 16 + l15) * 16);
            const s8b qh0 = *(const s8b*)(l_qh + ka + (wc      + l15) * 16);
            const s8b qh1 = *(const s8b*)(l_qh + ka + (wc + 16 + l15) * 16);
            const s8b ql0 = *(const s8b*)(l_ql + ka + (wc      + l15) * 16);
            const s8b ql1 = *(const s8b*)(l_ql + ka + (wc + 16 + l15) * 16);

            acc[0][0] = __builtin_amdgcn_mfma_f32_16x16x32_bf16(kh0, qh0, acc[0][0], 0, 0, 0);
            acc[0][1] = __builtin_amdgcn_mfma_f32_16x16x32_bf16(kh0, qh1, acc[0][1], 0, 0, 0);
            acc[1][0] = __builtin_amdgcn_mfma_f32_16x16x32_bf16(kh1, qh0, acc[1][0], 0, 0, 0);
            acc[1][1] = __builtin_amdgcn_mfma_f32_16x16x32_bf16(kh1, qh1, acc[1][1], 0, 0, 0);
            acc[0][0] = __builtin_amdgcn_mfma_f32_16x16x32_bf16(kh0, ql0, acc[0][0], 0, 0, 0);
            acc[0][1] = __builtin_amdgcn_mfma_f32_16x16x32_bf16(kh0, ql1, acc[0][1], 0, 0, 0);
            acc[1][0] = __builtin_amdgcn_mfma_f32_16x16x32_bf16(kh1, ql0, acc[1][0], 0, 0, 0);
            acc[1][1] = __builtin_amdgcn_mfma_f32_16x16x32_bf16(kh1, ql1, acc[1][1], 0, 0, 0);
            acc[0][0] = __builtin_amdgcn_mfma_f32_16x16x32_bf16(kl0, qh0, acc[0][0], 0, 0, 0);
            acc[0][1] = __builtin_amdgcn_mfma_f32_16x16x32_bf16(kl0, qh1, acc[0][1], 0, 0, 0);
            acc[1][0] = __builtin_amdgcn_mfma_f32_16x16x32_bf16(kl1, qh0, acc[1][0], 0, 0, 0);
            acc[1][1] = __builtin_amdgcn_mfma_f32_16x16x32_bf16(kl1, qh1, acc[1][1], 0, 0, 0);
        }

        // lane holds T[q][k0..k0+3]: q = wc+ns*16+l15, k0 = wr+ms*16+l4*4
        #pragma unroll
        for (int ms = 0; ms < 2; ++ms) {
            #pragma unroll
            for (int ns = 0; ns < 2; ++ns) {
                const int q  = wc + ns * 16 + l15;
                const int k0 = wr + ms * 16 + l4 * 4;
                *(float4*)&out[outbase + (size_t)q * LL + (size_t)n * QQ + k0] =
                    make_float4(acc[ms][ns][0], acc[ms][ns][1], acc[ms][ns][2], acc[ms][ns][3]);
            }
        }

        if (pre) WRITE_K(cur ^ 1, nk, nc);       // vmcnt waits land here

        __syncthreads();   // staged n+1 visible; buf cur free for overwrite
        cur ^= 1;
    }
}

// ---------------------------------------------------------------------------
extern "C" void kernel_launch(void* const* d_in, const int* in_sizes, int n_in,
                              void* d_out, int out_size, void* d_ws, size_t ws_size,
                              hipStream_t stream) {
    const float* x  = (const float*)d_in[0];
    const float* Wa = (const float*)d_in[1];
    const float* ba = (const float*)d_in[2];
    const float* Wb = (const float*)d_in[3];
    const float* bb = (const float*)d_in[4];
    const float* Wc = (const float*)d_in[5];
    const float* bc = (const float*)d_in[6];
    float* out = (float*)d_out;
    float* ws  = (float*)d_ws;

    const size_t NBLD = (size_t)BB * LL * DD;   // 1,048,576 floats
    float* logA = ws;
    float* Bf   = ws + 1 * NBLD;
    float* Cf   = ws + 2 * NBLD;
    float* qf   = ws + 4 * NBLD;
    float* kf   = ws + 5 * NBLD;
    float* coff = ws + 6 * NBLD;                        // 16*17*64 floats
    float* csum = coff + (size_t)BB * HH * 17 * DHD;    // 256*64 floats

    gemm3_fused<<<256, 512, 0, stream>>>(x, Wa, ba, Wb, bb, Wc, bc, logA, Bf, Cf, csum);
    scan_diag<<<BB * HH * NCC, 256, 0, stream>>>(logA, Bf, Cf, csum, qf, kf, coff, out);
    band_row<<<BB * HH * NCC * 2, 256, 0, stream>>>(qf, kf, coff, out);
}

// Round 17
// 75.947 us; speedup vs baseline: 1.1987x; 1.0131x over previous
//
#include <hip/hip_runtime.h>
#include <math.h>

#define BB 2
#define LL 1024
#define DD 512
#define HH 8
#define DHD 64
#define QQ 64
#define NCC 16

typedef __attribute__((ext_vector_type(8))) short s8b;   // 8 bf16 (4 VGPRs)
typedef __attribute__((ext_vector_type(4))) float f4;    // 4 fp32 acc

__device__ __forceinline__ void bf16split(float f, unsigned short& h, unsigned short& l) {
    unsigned u  = __float_as_uint(f);
    unsigned hb = (u + 0x7FFFu + ((u >> 16) & 1u)) & 0xFFFF0000u;   // RTNE bf16
    float fh = __uint_as_float(hb);
    float fl = f - fh;
    unsigned ul = __float_as_uint(fl);
    unsigned lb = (ul + 0x7FFFu + ((ul >> 16) & 1u)) >> 16;
    h = (unsigned short)(hb >> 16);
    l = (unsigned short)lb;
}

__device__ __forceinline__ unsigned pk2(unsigned short a, unsigned short b) {
    return (unsigned)a | ((unsigned)b << 16);
}

// ---------------------------------------------------------------------------
// Kernel 1: fused 3-weight MFMA GEMM with in-kernel bf16 hi/lo split
// (unchanged from R15/R16).
// ---------------------------------------------------------------------------
__global__ __launch_bounds__(512) void gemm3_fused(
    const float* __restrict__ x,
    const float* __restrict__ Wa, const float* __restrict__ ba,
    const float* __restrict__ Wb, const float* __restrict__ bb,
    const float* __restrict__ Wc, const float* __restrict__ bc,
    float* __restrict__ logA, float* __restrict__ Bf, float* __restrict__ Cf,
    float* __restrict__ csum)
{
    __shared__ unsigned char lds[65536];
    __shared__ float csv[64];

    const int bm = blockIdx.x >> 3;
    const int bn = blockIdx.x & 7;
    const int m0 = bm << 6, o0 = bn << 6;
    const int t = threadIdx.x, wv = t >> 6, ln = t & 63;
    const int l15 = ln & 15, l4 = ln >> 4;
    const int wr = (wv >> 2) << 5;      // 0 / 32
    const int wc = (wv & 3) << 4;       // 0 / 16 / 32 / 48

    const int src_id = wv >> 1;                       // 0=x,1=Wa,2=Wb,3=Wc
    const float* srcp =
        (src_id == 0) ? x + (size_t)m0 * DD :
        ((src_id == 1) ? Wa : (src_id == 2) ? Wb : Wc) + (size_t)o0 * DD;
    const int roff = ((wv & 1) << 5) + (ln >> 1);     // local row 0..63
    const int ksh  = (ln & 1) << 4;                   // k sub-offset 0/16
    const int swz  = (roff >> 1) & 3;
    const int sA   = ((ksh >> 3) + 0) ^ swz;
    const int sB   = ((ksh >> 3) + 1) ^ swz;
    const size_t srow = (size_t)roff * DD + ksh;
    const int hiBase = (src_id * 2) * 4096 + roff * 64;

    f4 acc[3][2] = {};

    auto STAGE = [&](int buf, int kt) {
        const float* p = srcp + srow + kt;
        const float4 f0 = *(const float4*)(p + 0);
        const float4 f1 = *(const float4*)(p + 4);
        const float4 f2 = *(const float4*)(p + 8);
        const float4 f3 = *(const float4*)(p + 12);
        const float v[16] = {f0.x,f0.y,f0.z,f0.w, f1.x,f1.y,f1.z,f1.w,
                             f2.x,f2.y,f2.z,f2.w, f3.x,f3.y,f3.z,f3.w};
        unsigned short h[16], l[16];
        #pragma unroll
        for (int i = 0; i < 16; ++i) bf16split(v[i], h[i], l[i]);
        unsigned char* bh = lds + buf * 32768 + hiBase;
        unsigned char* bl = bh + 4096;
        *(uint4*)(bh + sA * 16) = make_uint4(pk2(h[0],h[1]),  pk2(h[2],h[3]),
                                             pk2(h[4],h[5]),  pk2(h[6],h[7]));
        *(uint4*)(bh + sB * 16) = make_uint4(pk2(h[8],h[9]),  pk2(h[10],h[11]),
                                             pk2(h[12],h[13]),pk2(h[14],h[15]));
        *(uint4*)(bl + sA * 16) = make_uint4(pk2(l[0],l[1]),  pk2(l[2],l[3]),
                                             pk2(l[4],l[5]),  pk2(l[6],l[7]));
        *(uint4*)(bl + sB * 16) = make_uint4(pk2(l[8],l[9]),  pk2(l[10],l[11]),
                                             pk2(l[12],l[13]),pk2(l[14],l[15]));
    };

    auto ldso = [&](int row, int kg) {
        return row * 64 + ((kg ^ ((row >> 1) & 3)) << 4);
    };

    auto COMPUTE = [&](int buf) {
        const unsigned char* base = lds + buf * 32768;
        const s8b ah0 = *(const s8b*)(base + 0*4096 + ldso(wr      + l15, l4));
        const s8b ah1 = *(const s8b*)(base + 0*4096 + ldso(wr + 16 + l15, l4));
        const s8b al0 = *(const s8b*)(base + 1*4096 + ldso(wr      + l15, l4));
        const s8b al1 = *(const s8b*)(base + 1*4096 + ldso(wr + 16 + l15, l4));
        #pragma unroll
        for (int s = 0; s < 3; ++s) {
            const s8b bh = *(const s8b*)(base + (2 + 2*s)*4096 + ldso(wc + l15, l4));
            const s8b bl = *(const s8b*)(base + (3 + 2*s)*4096 + ldso(wc + l15, l4));
            acc[s][0] = __builtin_amdgcn_mfma_f32_16x16x32_bf16(ah0, bh, acc[s][0], 0, 0, 0);
            acc[s][1] = __builtin_amdgcn_mfma_f32_16x16x32_bf16(ah1, bh, acc[s][1], 0, 0, 0);
            acc[s][0] = __builtin_amdgcn_mfma_f32_16x16x32_bf16(ah0, bl, acc[s][0], 0, 0, 0);
            acc[s][1] = __builtin_amdgcn_mfma_f32_16x16x32_bf16(ah1, bl, acc[s][1], 0, 0, 0);
            acc[s][0] = __builtin_amdgcn_mfma_f32_16x16x32_bf16(al0, bh, acc[s][0], 0, 0, 0);
            acc[s][1] = __builtin_amdgcn_mfma_f32_16x16x32_bf16(al1, bh, acc[s][1], 0, 0, 0);
        }
    };

    STAGE(0, 0);
    __syncthreads();
    int cur = 0;
    for (int it = 0; it < 16; ++it) {
        if (it < 15) STAGE(cur ^ 1, (it + 1) * 32);
        COMPUTE(cur);
        __syncthreads();
        cur ^= 1;
    }

    const int col = o0 + wc + l15;
    const float bva = ba[col], bvb = bb[col], bvc = bc[col];
    float asum = 0.f;
    #pragma unroll
    for (int ms = 0; ms < 2; ++ms) {
        const int row0 = m0 + wr + ms * 16 + l4 * 4;
        #pragma unroll
        for (int r = 0; r < 4; ++r) {
            const size_t o = (size_t)(row0 + r) * DD + col;
            float va = acc[0][ms][r] + bva;
            va = fminf(va, 0.f) - log1pf(__expf(-fabsf(va)));   // logsigmoid
            logA[o] = va;
            asum += va;
            Bf[o] = acc[1][ms][r] + bvb;
            Cf[o] = acc[2][ms][r] + bvc;
        }
    }

    asum += __shfl_xor(asum, 16);
    asum += __shfl_xor(asum, 32);
    if (wv < 4 && l4 == 0) csv[wc + l15] = asum;
    __syncthreads();
    if (wv >= 4 && l4 == 0) {
        const int blkc = (((bm >> 4) * 8 + bn) << 4) + (bm & 15);   // (b*8+h)*16+c
        csum[(size_t)blkc * DHD + wc + l15] = csv[wc + l15] + asum;
    }
}

// ---------------------------------------------------------------------------
// Kernel 2: scan + fused diag tile + strict-upper zero-fill tail
// (unchanged from R16).
// ---------------------------------------------------------------------------
__global__ __launch_bounds__(256) void scan_diag(
    const float* __restrict__ logA, const float* __restrict__ Bf,
    const float* __restrict__ Cf, const float* __restrict__ csum,
    float* __restrict__ qf, float* __restrict__ kf,
    float* __restrict__ coff, float* __restrict__ out)
{
    __shared__ float part[4][DHD];
    __shared__ float smA[DHD][65];   // Cf stash [d][row]
    __shared__ float smB[DHD][65];   // Bf stash
    __shared__ float smC[DHD][65];   // Sloc stash

    const int blk = blockIdx.x;
    const int bh = blk >> 4, c = blk & 15;
    const int b = bh >> 3, h = bh & 7;
    const int t = threadIdx.x;
    const int d = t & 63, w = t >> 6;

    const size_t gbase = (size_t)(b * LL + c * QQ + w * 16) * DD + h * DHD + d;
    float lar[16];
    float ps = 0.f;
    #pragma unroll
    for (int i = 0; i < 16; ++i) {
        lar[i] = logA[gbase + (size_t)i * DD];
        ps += lar[i];
    }
    part[w][d] = ps;
    __syncthreads();

    const size_t cs0 = ((size_t)bh << 4) * DHD + d;
    float off = 0.f;
    for (int cc = 0; cc < c; ++cc) off += csum[cs0 + (size_t)cc * DHD];
    const float tot = part[0][d] + part[1][d] + part[2][d] + part[3][d];
    if (t < DHD) {
        coff[((size_t)bh * 17 + c) * DHD + t] = off;
        if (c == NCC - 1) coff[((size_t)bh * 17 + 16) * DHD + t] = off + tot;
    }

    float run = 0.f;
    for (int ww = 0; ww < 4; ++ww) if (ww < w) run += part[ww][d];

    const size_t hbase = ((size_t)bh * LL + c * QQ + w * 16) * DHD + d;
    #pragma unroll
    for (int i = 0; i < 16; ++i) {
        const size_t gi = gbase + (size_t)i * DD;
        const float cv = Cf[gi];
        const float bv = Bf[gi];
        qf[hbase + (size_t)i * DHD] = cv * __expf(run);       // exp(Sm1 - Eprev)
        run += lar[i];
        const int rloc = w * 16 + i;
        smC[d][rloc] = run;       // Sloc
        smA[d][rloc] = cv;        // C
        smB[d][rloc] = bv;        // B
        kf[hbase + (size_t)i * DHD] = bv * __expf(tot - run); // exp(E - S)
    }
    __syncthreads();

    // ---- diag tile compute ----
    const int q0 = ((t >> 4) & 15) << 2;
    const int k0 = (t & 15) << 2;

    float acc[4][4] = {};
    if (q0 + 3 >= k0) {
        #pragma unroll 2
        for (int dd = 0; dd < DHD; ++dd) {
            const float4 cq = *(const float4*)&smA[dd][q0];
            const float4 bk = *(const float4*)&smB[dd][k0];
            const float4 sk = *(const float4*)&smC[dd][k0];
            const float cqa[4] = {cq.x, cq.y, cq.z, cq.w};
            const float bka[4] = {bk.x, bk.y, bk.z, bk.w};
            const float ska[4] = {sk.x, sk.y, sk.z, sk.w};
            float s1a[4];
            #pragma unroll
            for (int i = 0; i < 4; ++i) {
                const int qi = q0 + i;
                s1a[i] = (qi == 0) ? 0.f : smC[dd][qi - 1];
            }
            #pragma unroll
            for (int i = 0; i < 4; ++i) {
                #pragma unroll
                for (int j = 0; j < 4; ++j) {
                    const int qi = q0 + i, kj = k0 + j;
                    const float wgt = (qi > kj) ? __expf(s1a[i] - ska[j])
                                                : ((qi == kj) ? 1.f : 0.f);
                    acc[i][j] += cqa[i] * wgt * bka[j];
                }
            }
        }
    }
    const size_t outrow0 = ((size_t)bh * LL + (size_t)c * QQ) * LL + (size_t)c * QQ;
    #pragma unroll
    for (int i = 0; i < 4; ++i)
        *(float4*)&out[outrow0 + (size_t)(q0 + i) * LL + k0] =
            make_float4(acc[i][0], acc[i][1], acc[i][2], acc[i][3]);

    // ---- strict-upper zero-fill (1920 tiles spread over 256 blocks) ----
    for (int z = blk; z < BB * HH * 120; z += 256) {
        const int zbh = z / 120;
        const int idx = z - zbh * 120;
        int a = (int)((1.0f + sqrtf(1.0f + 8.0f * (float)idx)) * 0.5f);
        if (a * (a - 1) / 2 > idx) --a;
        else if ((a + 1) * a / 2 <= idx) ++a;
        const int zm = idx - a * (a - 1) / 2;   // row-chunk
        const int zn = a;                       // col-chunk, zn > zm
        const size_t zb = ((size_t)zbh * LL + (size_t)zm * QQ) * LL + (size_t)zn * QQ;
        const float4 zz = make_float4(0.f, 0.f, 0.f, 0.f);
        #pragma unroll
        for (int r = 0; r < 4; ++r) {
            const int fi = t + (r << 8);        // float4 idx 0..1023
            const int row = fi >> 4;
            const int col = (fi & 15) << 2;
            *(float4*)&out[zb + (size_t)row * LL + col] = zz;
        }
    }
}

// ---------------------------------------------------------------------------
// Kernel 3: band v8 = R16 body + T1 XCD-aware grid decode:
//  blockIdx&7 (XCD id under round-robin dispatch) == bh&7, so each XCD's
//  private L2 keeps its two bh's kf/qf/coff (~2 MB) resident across the
//  whole band pass. Bijective: 8 xcd x 64 k = 512 = 16bh x 16m x 2half.
// ---------------------------------------------------------------------------
__global__ __launch_bounds__(256) void band_row(
    const float* __restrict__ qf, const float* __restrict__ kf,
    const float* __restrict__ coff, float* __restrict__ out)
{
    __shared__ unsigned char lds[49152];
    unsigned char* const l_qh = lds;
    unsigned char* const l_ql = lds + 8192;
    // k buffers: base 16384 + buf*16384, kh at +0, kl at +8192

    // T1 swizzle decode
    const int raw  = blockIdx.x;
    const int xcd  = raw & 7;
    const int kk   = raw >> 3;               // 0..63
    const int bh   = ((kk & 1) << 3) | xcd;  // XCD hosts bh=xcd and xcd+8
    const int rem  = kk >> 1;                // 0..31
    const int m    = rem >> 1;
    const int half = rem & 1;
    const int n0   = half << 3;

    const int t  = threadIdx.x;
    const int wv = t >> 6;
    const int ln = t & 63;
    const int l15 = ln & 15;
    const int l4  = ln >> 4;
    const int wr = (wv >> 1) << 5;           // k-side half (A operand)
    const int wc = (wv & 1) << 5;            // q-side half (B operand)

    const int srow = t >> 2;                 // 0..63
    const int skc  = (t & 3) << 4;           // 0/16/32/48
    const int slot0 = skc >> 3;

    const size_t cb = (size_t)bh * 17 * DHD;
    const size_t outbase = ((size_t)bh * LL + (size_t)m * QQ) * LL;

    const int ne = (m < n0 + 8) ? m : (n0 + 8);   // offdiag n in [n0, ne)
    if (n0 >= ne) return;

    // ---- coff[m] slice ----
    float cm[16];
    #pragma unroll
    for (int g = 0; g < 4; ++g) {
        const float4 a = *(const float4*)&coff[cb + (size_t)m * DHD + skc + g * 4];
        cm[g*4+0]=a.x; cm[g*4+1]=a.y; cm[g*4+2]=a.z; cm[g*4+3]=a.w;
    }

    // ---- stage qf_m once (hi/lo split) ----
    {
        const size_t qb = ((size_t)bh * LL + (size_t)m * QQ + srow) * DHD + skc;
        float v[16];
        #pragma unroll
        for (int g = 0; g < 4; ++g) {
            const float4 x4 = *(const float4*)&qf[qb + g * 4];
            v[g*4+0]=x4.x; v[g*4+1]=x4.y; v[g*4+2]=x4.z; v[g*4+3]=x4.w;
        }
        unsigned short h[16], l[16];
        #pragma unroll
        for (int i = 0; i < 16; ++i) bf16split(v[i], h[i], l[i]);
        *(uint4*)(l_qh + slot0*1024 + srow*16) =
            make_uint4(pk2(h[0],h[1]), pk2(h[2],h[3]), pk2(h[4],h[5]), pk2(h[6],h[7]));
        *(uint4*)(l_qh + (slot0+1)*1024 + srow*16) =
            make_uint4(pk2(h[8],h[9]), pk2(h[10],h[11]), pk2(h[12],h[13]), pk2(h[14],h[15]));
        *(uint4*)(l_ql + slot0*1024 + srow*16) =
            make_uint4(pk2(l[0],l[1]), pk2(l[2],l[3]), pk2(l[4],l[5]), pk2(l[6],l[7]));
        *(uint4*)(l_ql + (slot0+1)*1024 + srow*16) =
            make_uint4(pk2(l[8],l[9]), pk2(l[10],l[11]), pk2(l[12],l[13]), pk2(l[14],l[15]));
    }

    // ---- T14 split staging: LOAD (global->reg) / WRITE (exp+split+LDS) ----
    auto LOAD_K = [&](int n, float* vk, float* vc) {
        const size_t kb = ((size_t)bh * LL + (size_t)n * QQ + srow) * DHD + skc;
        #pragma unroll
        for (int g = 0; g < 4; ++g) {
            const float4 x4 = *(const float4*)&kf[kb + g * 4];
            vk[g*4+0]=x4.x; vk[g*4+1]=x4.y; vk[g*4+2]=x4.z; vk[g*4+3]=x4.w;
            const float4 c4 = *(const float4*)&coff[cb + (size_t)(n + 1) * DHD + skc + g * 4];
            vc[g*4+0]=c4.x; vc[g*4+1]=c4.y; vc[g*4+2]=c4.z; vc[g*4+3]=c4.w;
        }
    };

    auto WRITE_K = [&](int buf, const float* vk, const float* vc) {
        unsigned char* const kh_b = lds + 16384 + buf * 16384;
        unsigned char* const kl_b = kh_b + 8192;
        float v[16];
        #pragma unroll
        for (int i = 0; i < 16; ++i)
            v[i] = vk[i] * __expf(cm[i] - vc[i]);
        unsigned short h[16], l[16];
        #pragma unroll
        for (int i = 0; i < 16; ++i) bf16split(v[i], h[i], l[i]);
        *(uint4*)(kh_b + slot0*1024 + srow*16) =
            make_uint4(pk2(h[0],h[1]), pk2(h[2],h[3]), pk2(h[4],h[5]), pk2(h[6],h[7]));
        *(uint4*)(kh_b + (slot0+1)*1024 + srow*16) =
            make_uint4(pk2(h[8],h[9]), pk2(h[10],h[11]), pk2(h[12],h[13]), pk2(h[14],h[15]));
        *(uint4*)(kl_b + slot0*1024 + srow*16) =
            make_uint4(pk2(l[0],l[1]), pk2(l[2],l[3]), pk2(l[4],l[5]), pk2(l[6],l[7]));
        *(uint4*)(kl_b + (slot0+1)*1024 + srow*16) =
            make_uint4(pk2(l[8],l[9]), pk2(l[10],l[11]), pk2(l[12],l[13]), pk2(l[14],l[15]));
    };

    {
        float pk0[16], pc0[16];
        LOAD_K(n0, pk0, pc0);
        WRITE_K(0, pk0, pc0);
    }
    __syncthreads();

    int cur = 0;
    for (int n = n0; n < ne; ++n) {
        float nk[16], nc[16];
        const bool pre = (n + 1 < ne);
        if (pre) LOAD_K(n + 1, nk, nc);          // loads issue; no use yet

        const unsigned char* const kh_b = lds + 16384 + cur * 16384;
        const unsigned char* const kl_b = kh_b + 8192;

        f4 acc[2][2] = {};   // MFMA overlaps the in-flight loads
        #pragma unroll
        for (int ks = 0; ks < 2; ++ks) {
            const int ka = (ks * 4 + l4) * 1024;
            const s8b kh0 = *(const s8b*)(kh_b + ka + (wr      + l15) * 16);
            const s8b kh1 = *(const s8b*)(kh_b + ka + (wr + 16 + l15) * 16);
            const s8b kl0 = *(const s8b*)(kl_b + ka + (wr      + l15) * 16);
            const s8b kl1 = *(const s8b*)(kl_b + ka + (wr + 16 + l15) * 16);
            const s8b qh0 = *(const s8b*)(l_qh + ka + (wc      + l15) * 16);
            const s8b qh1 = *(const s8b*)(l_qh + ka + (wc + 16 + l15) * 16);
            const s8b ql0 = *(const s8b*)(l_ql + ka + (wc      + l15) * 16);
            const s8b ql1 = *(const s8b*)(l_ql + ka + (wc + 16 + l15) * 16);

            acc[0][0] = __builtin_amdgcn_mfma_f32_16x16x32_bf16(kh0, qh0, acc[0][0], 0, 0, 0);
            acc[0][1] = __builtin_amdgcn_mfma_f32_16x16x32_bf16(kh0, qh1, acc[0][1], 0, 0, 0);
            acc[1][0] = __builtin_amdgcn_mfma_f32_16x16x32_bf16(kh1, qh0, acc[1][0], 0, 0, 0);
            acc[1][1] = __builtin_amdgcn_mfma_f32_16x16x32_bf16(kh1, qh1, acc[1][1], 0, 0, 0);
            acc[0][0] = __builtin_amdgcn_mfma_f32_16x16x32_bf16(kh0, ql0, acc[0][0], 0, 0, 0);
            acc[0][1] = __builtin_amdgcn_mfma_f32_16x16x32_bf16(kh0, ql1, acc[0][1], 0, 0, 0);
            acc[1][0] = __builtin_amdgcn_mfma_f32_16x16x32_bf16(kh1, ql0, acc[1][0], 0, 0, 0);
            acc[1][1] = __builtin_amdgcn_mfma_f32_16x16x32_bf16(kh1, ql1, acc[1][1], 0, 0, 0);
            acc[0][0] = __builtin_amdgcn_mfma_f32_16x16x32_bf16(kl0, qh0, acc[0][0], 0, 0, 0);
            acc[0][1] = __builtin_amdgcn_mfma_f32_16x16x32_bf16(kl0, qh1, acc[0][1], 0, 0, 0);
            acc[1][0] = __builtin_amdgcn_mfma_f32_16x16x32_bf16(kl1, qh0, acc[1][0], 0, 0, 0);
            acc[1][1] = __builtin_amdgcn_mfma_f32_16x16x32_bf16(kl1, qh1, acc[1][1], 0, 0, 0);
        }

        // lane holds T[q][k0..k0+3]: q = wc+ns*16+l15, k0 = wr+ms*16+l4*4
        #pragma unroll
        for (int ms = 0; ms < 2; ++ms) {
            #pragma unroll
            for (int ns = 0; ns < 2; ++ns) {
                const int q  = wc + ns * 16 + l15;
                const int k0 = wr + ms * 16 + l4 * 4;
                *(float4*)&out[outbase + (size_t)q * LL + (size_t)n * QQ + k0] =
                    make_float4(acc[ms][ns][0], acc[ms][ns][1], acc[ms][ns][2], acc[ms][ns][3]);
            }
        }

        if (pre) WRITE_K(cur ^ 1, nk, nc);       // vmcnt waits land here

        __syncthreads();   // staged n+1 visible; buf cur free for overwrite
        cur ^= 1;
    }
}

// ---------------------------------------------------------------------------
extern "C" void kernel_launch(void* const* d_in, const int* in_sizes, int n_in,
                              void* d_out, int out_size, void* d_ws, size_t ws_size,
                              hipStream_t stream) {
    const float* x  = (const float*)d_in[0];
    const float* Wa = (const float*)d_in[1];
    const float* ba = (const float*)d_in[2];
    const float* Wb = (const float*)d_in[3];
    const float* bb = (const float*)d_in[4];
    const float* Wc = (const float*)d_in[5];
    const float* bc = (const float*)d_in[6];
    float* out = (float*)d_out;
    float* ws  = (float*)d_ws;

    const size_t NBLD = (size_t)BB * LL * DD;   // 1,048,576 floats
    float* logA = ws;
    float* Bf   = ws + 1 * NBLD;
    float* Cf   = ws + 2 * NBLD;
    float* qf   = ws + 4 * NBLD;
    float* kf   = ws + 5 * NBLD;
    float* coff = ws + 6 * NBLD;                        // 16*17*64 floats
    float* csum = coff + (size_t)BB * HH * 17 * DHD;    // 256*64 floats

    gemm3_fused<<<256, 512, 0, stream>>>(x, Wa, ba, Wb, bb, Wc, bc, logA, Bf, Cf, csum);
    scan_diag<<<BB * HH * NCC, 256, 0, stream>>>(logA, Bf, Cf, csum, qf, kf, coff, out);
    band_row<<<BB * HH * NCC * 2, 256, 0, stream>>>(qf, kf, coff, out);
}

// Round 18
// 74.297 us; speedup vs baseline: 1.2253x; 1.0222x over previous
//
#include <hip/hip_runtime.h>
#include <math.h>

#define BB 2
#define LL 1024
#define DD 512
#define HH 8
#define DHD 64
#define QQ 64
#define NCC 16

typedef __attribute__((ext_vector_type(8))) short s8b;   // 8 bf16 (4 VGPRs)
typedef __attribute__((ext_vector_type(4))) float f4;    // 4 fp32 acc

__device__ __forceinline__ void bf16split(float f, unsigned short& h, unsigned short& l) {
    unsigned u  = __float_as_uint(f);
    unsigned hb = (u + 0x7FFFu + ((u >> 16) & 1u)) & 0xFFFF0000u;   // RTNE bf16
    float fh = __uint_as_float(hb);
    float fl = f - fh;
    unsigned ul = __float_as_uint(fl);
    unsigned lb = (ul + 0x7FFFu + ((ul >> 16) & 1u)) >> 16;
    h = (unsigned short)(hb >> 16);
    l = (unsigned short)lb;
}

__device__ __forceinline__ unsigned pk2(unsigned short a, unsigned short b) {
    return (unsigned)a | ((unsigned)b << 16);
}

// ---------------------------------------------------------------------------
// Kernel 1: fused 3-weight MFMA GEMM with in-kernel bf16 hi/lo split
// (unchanged from R15-R17).
// ---------------------------------------------------------------------------
__global__ __launch_bounds__(512) void gemm3_fused(
    const float* __restrict__ x,
    const float* __restrict__ Wa, const float* __restrict__ ba,
    const float* __restrict__ Wb, const float* __restrict__ bb,
    const float* __restrict__ Wc, const float* __restrict__ bc,
    float* __restrict__ logA, float* __restrict__ Bf, float* __restrict__ Cf,
    float* __restrict__ csum)
{
    __shared__ unsigned char lds[65536];
    __shared__ float csv[64];

    const int bm = blockIdx.x >> 3;
    const int bn = blockIdx.x & 7;
    const int m0 = bm << 6, o0 = bn << 6;
    const int t = threadIdx.x, wv = t >> 6, ln = t & 63;
    const int l15 = ln & 15, l4 = ln >> 4;
    const int wr = (wv >> 2) << 5;      // 0 / 32
    const int wc = (wv & 3) << 4;       // 0 / 16 / 32 / 48

    const int src_id = wv >> 1;                       // 0=x,1=Wa,2=Wb,3=Wc
    const float* srcp =
        (src_id == 0) ? x + (size_t)m0 * DD :
        ((src_id == 1) ? Wa : (src_id == 2) ? Wb : Wc) + (size_t)o0 * DD;
    const int roff = ((wv & 1) << 5) + (ln >> 1);     // local row 0..63
    const int ksh  = (ln & 1) << 4;                   // k sub-offset 0/16
    const int swz  = (roff >> 1) & 3;
    const int sA   = ((ksh >> 3) + 0) ^ swz;
    const int sB   = ((ksh >> 3) + 1) ^ swz;
    const size_t srow = (size_t)roff * DD + ksh;
    const int hiBase = (src_id * 2) * 4096 + roff * 64;

    f4 acc[3][2] = {};

    auto STAGE = [&](int buf, int kt) {
        const float* p = srcp + srow + kt;
        const float4 f0 = *(const float4*)(p + 0);
        const float4 f1 = *(const float4*)(p + 4);
        const float4 f2 = *(const float4*)(p + 8);
        const float4 f3 = *(const float4*)(p + 12);
        const float v[16] = {f0.x,f0.y,f0.z,f0.w, f1.x,f1.y,f1.z,f1.w,
                             f2.x,f2.y,f2.z,f2.w, f3.x,f3.y,f3.z,f3.w};
        unsigned short h[16], l[16];
        #pragma unroll
        for (int i = 0; i < 16; ++i) bf16split(v[i], h[i], l[i]);
        unsigned char* bh = lds + buf * 32768 + hiBase;
        unsigned char* bl = bh + 4096;
        *(uint4*)(bh + sA * 16) = make_uint4(pk2(h[0],h[1]),  pk2(h[2],h[3]),
                                             pk2(h[4],h[5]),  pk2(h[6],h[7]));
        *(uint4*)(bh + sB * 16) = make_uint4(pk2(h[8],h[9]),  pk2(h[10],h[11]),
                                             pk2(h[12],h[13]),pk2(h[14],h[15]));
        *(uint4*)(bl + sA * 16) = make_uint4(pk2(l[0],l[1]),  pk2(l[2],l[3]),
                                             pk2(l[4],l[5]),  pk2(l[6],l[7]));
        *(uint4*)(bl + sB * 16) = make_uint4(pk2(l[8],l[9]),  pk2(l[10],l[11]),
                                             pk2(l[12],l[13]),pk2(l[14],l[15]));
    };

    auto ldso = [&](int row, int kg) {
        return row * 64 + ((kg ^ ((row >> 1) & 3)) << 4);
    };

    auto COMPUTE = [&](int buf) {
        const unsigned char* base = lds + buf * 32768;
        const s8b ah0 = *(const s8b*)(base + 0*4096 + ldso(wr      + l15, l4));
        const s8b ah1 = *(const s8b*)(base + 0*4096 + ldso(wr + 16 + l15, l4));
        const s8b al0 = *(const s8b*)(base + 1*4096 + ldso(wr      + l15, l4));
        const s8b al1 = *(const s8b*)(base + 1*4096 + ldso(wr + 16 + l15, l4));
        #pragma unroll
        for (int s = 0; s < 3; ++s) {
            const s8b bh = *(const s8b*)(base + (2 + 2*s)*4096 + ldso(wc + l15, l4));
            const s8b bl = *(const s8b*)(base + (3 + 2*s)*4096 + ldso(wc + l15, l4));
            acc[s][0] = __builtin_amdgcn_mfma_f32_16x16x32_bf16(ah0, bh, acc[s][0], 0, 0, 0);
            acc[s][1] = __builtin_amdgcn_mfma_f32_16x16x32_bf16(ah1, bh, acc[s][1], 0, 0, 0);
            acc[s][0] = __builtin_amdgcn_mfma_f32_16x16x32_bf16(ah0, bl, acc[s][0], 0, 0, 0);
            acc[s][1] = __builtin_amdgcn_mfma_f32_16x16x32_bf16(ah1, bl, acc[s][1], 0, 0, 0);
            acc[s][0] = __builtin_amdgcn_mfma_f32_16x16x32_bf16(al0, bh, acc[s][0], 0, 0, 0);
            acc[s][1] = __builtin_amdgcn_mfma_f32_16x16x32_bf16(al1, bh, acc[s][1], 0, 0, 0);
        }
    };

    STAGE(0, 0);
    __syncthreads();
    int cur = 0;
    for (int it = 0; it < 16; ++it) {
        if (it < 15) STAGE(cur ^ 1, (it + 1) * 32);
        COMPUTE(cur);
        __syncthreads();
        cur ^= 1;
    }

    const int col = o0 + wc + l15;
    const float bva = ba[col], bvb = bb[col], bvc = bc[col];
    float asum = 0.f;
    #pragma unroll
    for (int ms = 0; ms < 2; ++ms) {
        const int row0 = m0 + wr + ms * 16 + l4 * 4;
        #pragma unroll
        for (int r = 0; r < 4; ++r) {
            const size_t o = (size_t)(row0 + r) * DD + col;
            float va = acc[0][ms][r] + bva;
            va = fminf(va, 0.f) - log1pf(__expf(-fabsf(va)));   // logsigmoid
            logA[o] = va;
            asum += va;
            Bf[o] = acc[1][ms][r] + bvb;
            Cf[o] = acc[2][ms][r] + bvc;
        }
    }

    asum += __shfl_xor(asum, 16);
    asum += __shfl_xor(asum, 32);
    if (wv < 4 && l4 == 0) csv[wc + l15] = asum;
    __syncthreads();
    if (wv >= 4 && l4 == 0) {
        const int blkc = (((bm >> 4) * 8 + bn) << 4) + (bm & 15);   // (b*8+h)*16+c
        csum[(size_t)blkc * DHD + wc + l15] = csv[wc + l15] + asum;
    }
}

// ---------------------------------------------------------------------------
// Kernel 2: scan + fused diag tile + strict-upper zero-fill tail
// (unchanged from R16/R17).
// ---------------------------------------------------------------------------
__global__ __launch_bounds__(256) void scan_diag(
    const float* __restrict__ logA, const float* __restrict__ Bf,
    const float* __restrict__ Cf, const float* __restrict__ csum,
    float* __restrict__ qf, float* __restrict__ kf,
    float* __restrict__ coff, float* __restrict__ out)
{
    __shared__ float part[4][DHD];
    __shared__ float smA[DHD][65];   // Cf stash [d][row]
    __shared__ float smB[DHD][65];   // Bf stash
    __shared__ float smC[DHD][65];   // Sloc stash

    const int blk = blockIdx.x;
    const int bh = blk >> 4, c = blk & 15;
    const int b = bh >> 3, h = bh & 7;
    const int t = threadIdx.x;
    const int d = t & 63, w = t >> 6;

    const size_t gbase = (size_t)(b * LL + c * QQ + w * 16) * DD + h * DHD + d;
    float lar[16];
    float ps = 0.f;
    #pragma unroll
    for (int i = 0; i < 16; ++i) {
        lar[i] = logA[gbase + (size_t)i * DD];
        ps += lar[i];
    }
    part[w][d] = ps;
    __syncthreads();

    const size_t cs0 = ((size_t)bh << 4) * DHD + d;
    float off = 0.f;
    for (int cc = 0; cc < c; ++cc) off += csum[cs0 + (size_t)cc * DHD];
    const float tot = part[0][d] + part[1][d] + part[2][d] + part[3][d];
    if (t < DHD) {
        coff[((size_t)bh * 17 + c) * DHD + t] = off;
        if (c == NCC - 1) coff[((size_t)bh * 17 + 16) * DHD + t] = off + tot;
    }

    float run = 0.f;
    for (int ww = 0; ww < 4; ++ww) if (ww < w) run += part[ww][d];

    const size_t hbase = ((size_t)bh * LL + c * QQ + w * 16) * DHD + d;
    #pragma unroll
    for (int i = 0; i < 16; ++i) {
        const size_t gi = gbase + (size_t)i * DD;
        const float cv = Cf[gi];
        const float bv = Bf[gi];
        qf[hbase + (size_t)i * DHD] = cv * __expf(run);       // exp(Sm1 - Eprev)
        run += lar[i];
        const int rloc = w * 16 + i;
        smC[d][rloc] = run;       // Sloc
        smA[d][rloc] = cv;        // C
        smB[d][rloc] = bv;        // B
        kf[hbase + (size_t)i * DHD] = bv * __expf(tot - run); // exp(E - S)
    }
    __syncthreads();

    // ---- diag tile compute ----
    const int q0 = ((t >> 4) & 15) << 2;
    const int k0 = (t & 15) << 2;

    float acc[4][4] = {};
    if (q0 + 3 >= k0) {
        #pragma unroll 2
        for (int dd = 0; dd < DHD; ++dd) {
            const float4 cq = *(const float4*)&smA[dd][q0];
            const float4 bk = *(const float4*)&smB[dd][k0];
            const float4 sk = *(const float4*)&smC[dd][k0];
            const float cqa[4] = {cq.x, cq.y, cq.z, cq.w};
            const float bka[4] = {bk.x, bk.y, bk.z, bk.w};
            const float ska[4] = {sk.x, sk.y, sk.z, sk.w};
            float s1a[4];
            #pragma unroll
            for (int i = 0; i < 4; ++i) {
                const int qi = q0 + i;
                s1a[i] = (qi == 0) ? 0.f : smC[dd][qi - 1];
            }
            #pragma unroll
            for (int i = 0; i < 4; ++i) {
                #pragma unroll
                for (int j = 0; j < 4; ++j) {
                    const int qi = q0 + i, kj = k0 + j;
                    const float wgt = (qi > kj) ? __expf(s1a[i] - ska[j])
                                                : ((qi == kj) ? 1.f : 0.f);
                    acc[i][j] += cqa[i] * wgt * bka[j];
                }
            }
        }
    }
    const size_t outrow0 = ((size_t)bh * LL + (size_t)c * QQ) * LL + (size_t)c * QQ;
    #pragma unroll
    for (int i = 0; i < 4; ++i)
        *(float4*)&out[outrow0 + (size_t)(q0 + i) * LL + k0] =
            make_float4(acc[i][0], acc[i][1], acc[i][2], acc[i][3]);

    // ---- strict-upper zero-fill (1920 tiles spread over 256 blocks) ----
    for (int z = blk; z < BB * HH * 120; z += 256) {
        const int zbh = z / 120;
        const int idx = z - zbh * 120;
        int a = (int)((1.0f + sqrtf(1.0f + 8.0f * (float)idx)) * 0.5f);
        if (a * (a - 1) / 2 > idx) --a;
        else if ((a + 1) * a / 2 <= idx) ++a;
        const int zm = idx - a * (a - 1) / 2;   // row-chunk
        const int zn = a;                       // col-chunk, zn > zm
        const size_t zb = ((size_t)zbh * LL + (size_t)zm * QQ) * LL + (size_t)zn * QQ;
        const float4 zz = make_float4(0.f, 0.f, 0.f, 0.f);
        #pragma unroll
        for (int r = 0; r < 4; ++r) {
            const int fi = t + (r << 8);        // float4 idx 0..1023
            const int row = fi >> 4;
            const int col = (fi & 15) << 2;
            *(float4*)&out[zb + (size_t)row * LL + col] = zz;
        }
    }
}

// ---------------------------------------------------------------------------
// Kernel 3: band v9 = R17 body at 4-tile granularity (grid 1024) + T1 decode.
//  blockIdx&7 == XCD id == bh&7; each block owns n in [4*q4, 4*q4+4).
//  Max 4 serial tiles/block (was 8) -> better balance, 3 blocks/CU.
// ---------------------------------------------------------------------------
__global__ __launch_bounds__(256) void band_row(
    const float* __restrict__ qf, const float* __restrict__ kf,
    const float* __restrict__ coff, float* __restrict__ out)
{
    __shared__ unsigned char lds[49152];
    unsigned char* const l_qh = lds;
    unsigned char* const l_ql = lds + 8192;
    // k buffers: base 16384 + buf*16384, kh at +0, kl at +8192

    // T1 swizzle decode (bijective over 1024 = 8 xcd x 128)
    const int raw  = blockIdx.x;
    const int xcd  = raw & 7;
    const int kk   = raw >> 3;               // 0..127
    const int bh   = ((kk & 1) << 3) | xcd;  // XCD hosts bh=xcd and xcd+8
    const int rem  = kk >> 1;                // 0..63
    const int m    = rem >> 2;
    const int q4   = rem & 3;
    const int n0   = q4 << 2;

    const int t  = threadIdx.x;
    const int wv = t >> 6;
    const int ln = t & 63;
    const int l15 = ln & 15;
    const int l4  = ln >> 4;
    const int wr = (wv >> 1) << 5;           // k-side half (A operand)
    const int wc = (wv & 1) << 5;            // q-side half (B operand)

    const int srow = t >> 2;                 // 0..63
    const int skc  = (t & 3) << 4;           // 0/16/32/48
    const int slot0 = skc >> 3;

    const size_t cb = (size_t)bh * 17 * DHD;
    const size_t outbase = ((size_t)bh * LL + (size_t)m * QQ) * LL;

    const int ne = (m < n0 + 4) ? m : (n0 + 4);   // offdiag n in [n0, ne)
    if (n0 >= ne) return;

    // ---- coff[m] slice ----
    float cm[16];
    #pragma unroll
    for (int g = 0; g < 4; ++g) {
        const float4 a = *(const float4*)&coff[cb + (size_t)m * DHD + skc + g * 4];
        cm[g*4+0]=a.x; cm[g*4+1]=a.y; cm[g*4+2]=a.z; cm[g*4+3]=a.w;
    }

    // ---- stage qf_m once (hi/lo split) ----
    {
        const size_t qb = ((size_t)bh * LL + (size_t)m * QQ + srow) * DHD + skc;
        float v[16];
        #pragma unroll
        for (int g = 0; g < 4; ++g) {
            const float4 x4 = *(const float4*)&qf[qb + g * 4];
            v[g*4+0]=x4.x; v[g*4+1]=x4.y; v[g*4+2]=x4.z; v[g*4+3]=x4.w;
        }
        unsigned short h[16], l[16];
        #pragma unroll
        for (int i = 0; i < 16; ++i) bf16split(v[i], h[i], l[i]);
        *(uint4*)(l_qh + slot0*1024 + srow*16) =
            make_uint4(pk2(h[0],h[1]), pk2(h[2],h[3]), pk2(h[4],h[5]), pk2(h[6],h[7]));
        *(uint4*)(l_qh + (slot0+1)*1024 + srow*16) =
            make_uint4(pk2(h[8],h[9]), pk2(h[10],h[11]), pk2(h[12],h[13]), pk2(h[14],h[15]));
        *(uint4*)(l_ql + slot0*1024 + srow*16) =
            make_uint4(pk2(l[0],l[1]), pk2(l[2],l[3]), pk2(l[4],l[5]), pk2(l[6],l[7]));
        *(uint4*)(l_ql + (slot0+1)*1024 + srow*16) =
            make_uint4(pk2(l[8],l[9]), pk2(l[10],l[11]), pk2(l[12],l[13]), pk2(l[14],l[15]));
    }

    // ---- T14 split staging: LOAD (global->reg) / WRITE (exp+split+LDS) ----
    auto LOAD_K = [&](int n, float* vk, float* vc) {
        const size_t kb = ((size_t)bh * LL + (size_t)n * QQ + srow) * DHD + skc;
        #pragma unroll
        for (int g = 0; g < 4; ++g) {
            const float4 x4 = *(const float4*)&kf[kb + g * 4];
            vk[g*4+0]=x4.x; vk[g*4+1]=x4.y; vk[g*4+2]=x4.z; vk[g*4+3]=x4.w;
            const float4 c4 = *(const float4*)&coff[cb + (size_t)(n + 1) * DHD + skc + g * 4];
            vc[g*4+0]=c4.x; vc[g*4+1]=c4.y; vc[g*4+2]=c4.z; vc[g*4+3]=c4.w;
        }
    };

    auto WRITE_K = [&](int buf, const float* vk, const float* vc) {
        unsigned char* const kh_b = lds + 16384 + buf * 16384;
        unsigned char* const kl_b = kh_b + 8192;
        float v[16];
        #pragma unroll
        for (int i = 0; i < 16; ++i)
            v[i] = vk[i] * __expf(cm[i] - vc[i]);
        unsigned short h[16], l[16];
        #pragma unroll
        for (int i = 0; i < 16; ++i) bf16split(v[i], h[i], l[i]);
        *(uint4*)(kh_b + slot0*1024 + srow*16) =
            make_uint4(pk2(h[0],h[1]), pk2(h[2],h[3]), pk2(h[4],h[5]), pk2(h[6],h[7]));
        *(uint4*)(kh_b + (slot0+1)*1024 + srow*16) =
            make_uint4(pk2(h[8],h[9]), pk2(h[10],h[11]), pk2(h[12],h[13]), pk2(h[14],h[15]));
        *(uint4*)(kl_b + slot0*1024 + srow*16) =
            make_uint4(pk2(l[0],l[1]), pk2(l[2],l[3]), pk2(l[4],l[5]), pk2(l[6],l[7]));
        *(uint4*)(kl_b + (slot0+1)*1024 + srow*16) =
            make_uint4(pk2(l[8],l[9]), pk2(l[10],l[11]), pk2(l[12],l[13]), pk2(l[14],l[15]));
    };

    {
        float pk0[16], pc0[16];
        LOAD_K(n0, pk0, pc0);
        WRITE_K(0, pk0, pc0);
    }
    __syncthreads();

    int cur = 0;
    for (int n = n0; n < ne; ++n) {
        float nk[16], nc[16];
        const bool pre = (n + 1 < ne);
        if (pre) LOAD_K(n + 1, nk, nc);          // loads issue; no use yet

        const unsigned char* const kh_b = lds + 16384 + cur * 16384;
        const unsigned char* const kl_b = kh_b + 8192;

        f4 acc[2][2] = {};   // MFMA overlaps the in-flight loads
        #pragma unroll
        for (int ks = 0; ks < 2; ++ks) {
            const int ka = (ks * 4 + l4) * 1024;
            const s8b kh0 = *(const s8b*)(kh_b + ka + (wr      + l15) * 16);
            const s8b kh1 = *(const s8b*)(kh_b + ka + (wr + 16 + l15) * 16);
            const s8b kl0 = *(const s8b*)(kl_b + ka + (wr      + l15) * 16);
            const s8b kl1 = *(const s8b*)(kl_b + ka + (wr + 16 + l15) * 16);
            const s8b qh0 = *(const s8b*)(l_qh + ka + (wc      + l15) * 16);
            const s8b qh1 = *(const s8b*)(l_qh + ka + (wc + 16 + l15) * 16);
            const s8b ql0 = *(const s8b*)(l_ql + ka + (wc      + l15) * 16);
            const s8b ql1 = *(const s8b*)(l_ql + ka + (wc + 16 + l15) * 16);

            acc[0][0] = __builtin_amdgcn_mfma_f32_16x16x32_bf16(kh0, qh0, acc[0][0], 0, 0, 0);
            acc[0][1] = __builtin_amdgcn_mfma_f32_16x16x32_bf16(kh0, qh1, acc[0][1], 0, 0, 0);
            acc[1][0] = __builtin_amdgcn_mfma_f32_16x16x32_bf16(kh1, qh0, acc[1][0], 0, 0, 0);
            acc[1][1] = __builtin_amdgcn_mfma_f32_16x16x32_bf16(kh1, qh1, acc[1][1], 0, 0, 0);
            acc[0][0] = __builtin_amdgcn_mfma_f32_16x16x32_bf16(kh0, ql0, acc[0][0], 0, 0, 0);
            acc[0][1] = __builtin_amdgcn_mfma_f32_16x16x32_bf16(kh0, ql1, acc[0][1], 0, 0, 0);
            acc[1][0] = __builtin_amdgcn_mfma_f32_16x16x32_bf16(kh1, ql0, acc[1][0], 0, 0, 0);
            acc[1][1] = __builtin_amdgcn_mfma_f32_16x16x32_bf16(kh1, ql1, acc[1][1], 0, 0, 0);
            acc[0][0] = __builtin_amdgcn_mfma_f32_16x16x32_bf16(kl0, qh0, acc[0][0], 0, 0, 0);
            acc[0][1] = __builtin_amdgcn_mfma_f32_16x16x32_bf16(kl0, qh1, acc[0][1], 0, 0, 0);
            acc[1][0] = __builtin_amdgcn_mfma_f32_16x16x32_bf16(kl1, qh0, acc[1][0], 0, 0, 0);
            acc[1][1] = __builtin_amdgcn_mfma_f32_16x16x32_bf16(kl1, qh1, acc[1][1], 0, 0, 0);
        }

        // lane holds T[q][k0..k0+3]: q = wc+ns*16+l15, k0 = wr+ms*16+l4*4
        #pragma unroll
        for (int ms = 0; ms < 2; ++ms) {
            #pragma unroll
            for (int ns = 0; ns < 2; ++ns) {
                const int q  = wc + ns * 16 + l15;
                const int k0 = wr + ms * 16 + l4 * 4;
                *(float4*)&out[outbase + (size_t)q * LL + (size_t)n * QQ + k0] =
                    make_float4(acc[ms][ns][0], acc[ms][ns][1], acc[ms][ns][2], acc[ms][ns][3]);
            }
        }

        if (pre) WRITE_K(cur ^ 1, nk, nc);       // vmcnt waits land here

        __syncthreads();   // staged n+1 visible; buf cur free for overwrite
        cur ^= 1;
    }
}

// ---------------------------------------------------------------------------
extern "C" void kernel_launch(void* const* d_in, const int* in_sizes, int n_in,
                              void* d_out, int out_size, void* d_ws, size_t ws_size,
                              hipStream_t stream) {
    const float* x  = (const float*)d_in[0];
    const float* Wa = (const float*)d_in[1];
    const float* ba = (const float*)d_in[2];
    const float* Wb = (const float*)d_in[3];
    const float* bb = (const float*)d_in[4];
    const float* Wc = (const float*)d_in[5];
    const float* bc = (const float*)d_in[6];
    float* out = (float*)d_out;
    float* ws  = (float*)d_ws;

    const size_t NBLD = (size_t)BB * LL * DD;   // 1,048,576 floats
    float* logA = ws;
    float* Bf   = ws + 1 * NBLD;
    float* Cf   = ws + 2 * NBLD;
    float* qf   = ws + 4 * NBLD;
    float* kf   = ws + 5 * NBLD;
    float* coff = ws + 6 * NBLD;                        // 16*17*64 floats
    float* csum = coff + (size_t)BB * HH * 17 * DHD;    // 256*64 floats

    gemm3_fused<<<256, 512, 0, stream>>>(x, Wa, ba, Wb, bb, Wc, bc, logA, Bf, Cf, csum);
    scan_diag<<<BB * HH * NCC, 256, 0, stream>>>(logA, Bf, Cf, csum, qf, kf, coff, out);
    band_row<<<BB * HH * NCC * 4, 256, 0, stream>>>(qf, kf, coff, out);
}